// Round 7
// baseline (504.701 us; speedup 1.0000x reference)
//
#include <hip/hip_runtime.h>

#define EPSB 1e-5f

// problem sizes
#define B_   8
#define C_   512
#define T_   8
#define HW_  784
#define S_   6272     // T*HW
#define R_   64
#define CQ_  128
#define K_   4
#define P_   512      // T*R

typedef _Float16 f16;
typedef __attribute__((ext_vector_type(8))) _Float16 f16x8;
typedef __attribute__((ext_vector_type(4))) _Float16 f16x4;
typedef __attribute__((ext_vector_type(4))) float    f32x4;

// ---- workspace byte offsets ----
#define OB_PTST  0ull                       // f16 [8][512][512]
#define OB_TC    4194304ull                 // f16 [8][512][512]
#define OB_D     8388608ull                 // f32 [8][6272]
#define OB_TRH   8589312ull                 // f16 [512][512]   (b*64+r rows)
#define OB_TRF   9113600ull                 // f32 [512][512]
#define OB_INDS  10162176ull                // int [8][4][8][64]
#define OB_WRH   10227712ull                // f16 [64][512]
#define OB_WPH   10293248ull                // f16 [128][512]  (w_proj cols 0..511)
#define OB_WTH   10424320ull                // f16 [512][3][128] (w_t repacked)
#define OB_XT    10817536ull                // f16 [8][6272][512]  51,380,224
// transients (region reused over time; all dead before the gemm chunks)
#define T_TPA    62197760ull                // f32 [512][784]    1,605,632  (dead after targmax)
#define T_AFF    63803392ull                // f32 [512][6272]  12,845,056  (dead after topk)
#define T_FUSEK  62197760ull                // f16 [32][512][128] (written after tpa dead)
#define T_FUSE   66392064ull                // f16 [8][512][128]  (fuseT, p-major)
#define CHB      62197760ull                // chunk region base (after conv everything above is dead)

#define SBAR()  __builtin_amdgcn_s_barrier()
#define SCHB()  __builtin_amdgcn_sched_barrier(0)
#define WAITV(N) asm volatile("s_waitcnt vmcnt(" #N ")" ::: "memory")

__device__ __forceinline__ void gload16(const void* g, void* l) {
    __builtin_amdgcn_global_load_lds(
        (const __attribute__((address_space(1))) unsigned int*)g,
        (__attribute__((address_space(3))) unsigned int*)l, 16, 0, 0);
}

// ============================================================
// P0: convert w_reduce -> f16 (32768), w_proj cols 0..511 -> f16 (65536),
//     w_t repack -> wth[co][dt][ci] f16 (196608)
__global__ __launch_bounds__(256) void k_prep(
    const float* __restrict__ wr, const float* __restrict__ wp,
    const float* __restrict__ wt,
    f16* __restrict__ wrh, f16* __restrict__ wph, f16* __restrict__ wth)
{
    int i = blockIdx.x*256 + threadIdx.x;   // 294912
    if (i < 32768) {
        wrh[i] = (f16)wr[i];
    } else if (i < 98304) {
        int j = i - 32768;
        int q = j >> 9, c = j & 511;
        wph[j] = (f16)wp[q*514 + c];
    } else {
        int j = i - 98304;                  // 196608 = 512*384
        int co = j / 384;
        int rem = j - co*384;
        int dt = rem >> 7, ci = rem & 127;
        wth[j] = (f16)wt[(size_t)(co*CQ_ + ci)*3 + dt];
    }
}

// ============================================================
// K0: transpose+convert x[b][c][s] f32 -> xT[b][s][c] f16
__global__ __launch_bounds__(256) void k_xpose(
    const float* __restrict__ x, f16* __restrict__ xT)
{
    __shared__ float tile[64][65];
    int s0 = blockIdx.x*64, c0 = blockIdx.y*64, b = blockIdx.z;
    int tid = threadIdx.x;
    #pragma unroll
    for (int i = 0; i < 4; ++i) {
        int idx = tid + i*256;
        int cl = idx >> 4, s4 = (idx & 15)*4;
        f32x4 v = *(const f32x4*)&x[((size_t)(b*C_ + c0+cl))*S_ + s0 + s4];
        tile[cl][s4] = v.x; tile[cl][s4+1] = v.y;
        tile[cl][s4+2] = v.z; tile[cl][s4+3] = v.w;
    }
    __syncthreads();
    #pragma unroll
    for (int i = 0; i < 4; ++i) {
        int idx = tid + i*256;
        int sl = idx >> 4, c4 = (idx & 15)*4;
        f16x4 h;
        h[0] = (f16)tile[c4+0][sl]; h[1] = (f16)tile[c4+1][sl];
        h[2] = (f16)tile[c4+2][sl]; h[3] = (f16)tile[c4+3][sl];
        *(f16x4*)&xT[((size_t)(b*S_ + s0+sl))*C_ + c0 + c4] = h;
    }
}

// ============================================================
// K1: template dots via MFMA: tpa[b*64+r][s] = sum_c wrh[r][c]*xT[b][s][c]
// grid (7, 8): tile 128s x 64r, BK=64, dbuf + counted vmcnt
__global__ __launch_bounds__(256) void k_templ(
    const f16* __restrict__ xT, const f16* __restrict__ wrh,
    float* __restrict__ tpa)
{
    __shared__ __align__(16) f16 As[2][128*64];
    __shared__ __align__(16) f16 Bs[2][64*64];
    int b = blockIdx.y; int s0 = blockIdx.x*128;
    int tid = threadIdx.x;
    int lane = tid & 63, w = tid >> 6;
    int lrow = lane >> 3;
    int swzc = ((lane & 7) ^ lrow) * 8;
    const f16* ga = xT  + ((size_t)b*S_ + s0 + w*32 + lrow)*C_ + swzc;
    const f16* gb = wrh + (size_t)(w*16 + lrow)*C_ + swzc;
    int mbase = (w & 1)*64, nbase = (w >> 1)*32;
    int fr = lane & 15, quad = lane >> 4;
    int sw = fr & 7;
    f32x4 acc[4][2] = {};
    #pragma unroll
    for (int j = 0; j < 4; ++j)
        gload16(ga + j*8*C_, &As[0][(w*32 + j*8)*64]);
    #pragma unroll
    for (int j = 0; j < 2; ++j)
        gload16(gb + j*8*C_, &Bs[0][(w*16 + j*8)*64]);
    ga += 64; gb += 64;
    int cur = 0;
    for (int i = 0; i < 8; ++i) {
        if (i < 7) {
            #pragma unroll
            for (int j = 0; j < 4; ++j)
                gload16(ga + j*8*C_, &As[cur^1][(w*32 + j*8)*64]);
            #pragma unroll
            for (int j = 0; j < 2; ++j)
                gload16(gb + j*8*C_, &Bs[cur^1][(w*16 + j*8)*64]);
            ga += 64; gb += 64;
            WAITV(6);
        } else {
            WAITV(0);
        }
        SCHB(); SBAR();
        #pragma unroll
        for (int kk = 0; kk < 2; ++kk) {
            int ch = ((kk*4 + quad) ^ sw) * 8;
            f16x8 af[4], bf[2];
            #pragma unroll
            for (int mt = 0; mt < 4; ++mt)
                af[mt] = *(const f16x8*)&As[cur][(mbase + mt*16 + fr)*64 + ch];
            #pragma unroll
            for (int nt = 0; nt < 2; ++nt)
                bf[nt] = *(const f16x8*)&Bs[cur][(nbase + nt*16 + fr)*64 + ch];
            #pragma unroll
            for (int mt = 0; mt < 4; ++mt)
                #pragma unroll
                for (int nt = 0; nt < 2; ++nt)
                    acc[mt][nt] = __builtin_amdgcn_mfma_f32_16x16x32_f16(
                        af[mt], bf[nt], acc[mt][nt], 0, 0, 0);
        }
        SBAR();
        cur ^= 1;
    }
    #pragma unroll
    for (int mt = 0; mt < 4; ++mt) {
        int sb = s0 + mbase + mt*16 + quad*4;
        if (sb < HW_) {
            #pragma unroll
            for (int nt = 0; nt < 2; ++nt) {
                int r = nbase + nt*16 + fr;
                *(f32x4*)&tpa[((size_t)(b*R_ + r))*HW_ + sb] = acc[mt][nt];
            }
        }
    }
}

// ============================================================
// K2: per (b,r): approx argmax of tpa*sc, gap-guarded exact fp32 fallback,
//     then gather tr row (f32 + f16)
// grid 512 = b*64+r
__global__ __launch_bounds__(256) void k_targmax(
    const float* __restrict__ x, const float* __restrict__ wr_g,
    const float* __restrict__ g1, const float* __restrict__ v1,
    const float* __restrict__ tpa,
    float* __restrict__ trf, f16* __restrict__ trh)
{
    __shared__ float row[HW_];
    __shared__ float sval[256];
    __shared__ int   sidx[256];
    __shared__ float cval[4];
    __shared__ int   cidx[4];
    __shared__ float eval_[4];
    __shared__ int   bestind;
    int bid = blockIdx.x;
    int b = bid >> 6, r = bid & 63;
    int tid = threadIdx.x;
    float sc = g1[r] * rsqrtf(v1[r] + EPSB);
    const float* tprow = tpa + (size_t)bid*HW_;
    for (int s = tid; s < HW_; s += 256) row[s] = tprow[s]*sc;
    __syncthreads();
    for (int pass = 0; pass < 4; ++pass) {
        float best = -INFINITY; int bi = 0;
        for (int s = tid; s < HW_; s += 256) {
            float v = row[s];
            if (v > best) { best = v; bi = s; }
        }
        sval[tid] = best; sidx[tid] = bi;
        __syncthreads();
        for (int off = 128; off > 0; off >>= 1) {
            if (tid < off) {
                float ov = sval[tid+off]; int oi = sidx[tid+off];
                if (ov > sval[tid] || (ov == sval[tid] && oi < sidx[tid])) {
                    sval[tid] = ov; sidx[tid] = oi;
                }
            }
            __syncthreads();
        }
        if (tid == 0) {
            cval[pass] = sval[0]; cidx[pass] = sidx[0];
            row[sidx[0]] = -INFINITY;
        }
        __syncthreads();
    }
    float thr = 0.05f * fabsf(sc);
    if (cval[0] - cval[1] >= thr) {
        if (tid == 0) bestind = cidx[0];
    } else {
        // exact fp32 recompute of the 4 candidates
        int w = tid >> 6, lane = tid & 63;
        int cand = cidx[w];
        float sum = 0.f;
        #pragma unroll
        for (int i = 0; i < 8; ++i) {
            int c = lane + i*64;
            sum += wr_g[r*C_ + c] * x[((size_t)(b*C_ + c))*S_ + cand];
        }
        #pragma unroll
        for (int off = 32; off > 0; off >>= 1) sum += __shfl_xor(sum, off);
        if (lane == 0) eval_[w] = sum*sc;
        __syncthreads();
        if (tid == 0) {
            float bv = eval_[0]; int bi2 = cidx[0];
            for (int j = 1; j < 4; ++j) {
                float v = eval_[j]; int ii = cidx[j];
                if (v > bv || (v == bv && ii < bi2)) { bv = v; bi2 = ii; }
            }
            bestind = bi2;
        }
    }
    __syncthreads();
    int ind = bestind;
    for (int c = tid; c < C_; c += 256) {
        float v = x[((size_t)(b*C_ + c))*S_ + ind];
        trf[(size_t)bid*C_ + c] = v;
        trh[(size_t)bid*C_ + c] = (f16)v;
    }
}

// ============================================================
// K3: affinity via MFMA: aff[b*64+r][s] = sum_c trh[b*64+r][c]*xT[b][s][c]
// grid (49, 8): tile 128s x 64r; BK=32 dbuf + counted vmcnt, 24 KB LDS
__global__ __launch_bounds__(256) void k_affin(
    const f16* __restrict__ xT, const f16* __restrict__ trh,
    float* __restrict__ aff)
{
    __shared__ __align__(16) f16 As[2][128*32];
    __shared__ __align__(16) f16 Bs[2][64*32];
    int b = blockIdx.y; int s0 = blockIdx.x*128;
    int tid = threadIdx.x;
    int lane = tid & 63, w = tid >> 6;
    int strow = tid >> 2;                   // 0..63
    int slot  = (tid & 3) ^ (strow & 3);
    const f16* ga = xT  + ((size_t)b*S_ + s0 + strow)*C_ + slot*8;
    const f16* gb = trh + ((size_t)(b*R_) + strow)*C_ + slot*8;
    int mbase = (w & 1)*64, nbase = (w >> 1)*32;
    int fr = lane & 15, quad = lane >> 4;
    f32x4 acc[4][2] = {};
    // prologue (A rows 64..127 at f16 offset 64*32 = 2048)
    gload16(ga,         (f16*)As[0] + tid*8);
    gload16(ga + 64*C_, (f16*)As[0] + 2048 + tid*8);
    gload16(gb,         (f16*)Bs[0] + tid*8);
    ga += 32; gb += 32;
    int cur = 0;
    for (int i = 0; i < 16; ++i) {
        if (i < 15) {
            gload16(ga,         (f16*)As[cur^1] + tid*8);
            gload16(ga + 64*C_, (f16*)As[cur^1] + 2048 + tid*8);
            gload16(gb,         (f16*)Bs[cur^1] + tid*8);
            ga += 32; gb += 32;
            WAITV(3);
        } else {
            WAITV(0);
        }
        SCHB(); SBAR();
        f16x8 af[4], bf[2];
        #pragma unroll
        for (int mt = 0; mt < 4; ++mt) {
            int ar = mbase + mt*16 + fr;
            af[mt] = *(const f16x8*)&As[cur][ar*32 + ((quad ^ (ar & 3))*8)];
        }
        #pragma unroll
        for (int nt = 0; nt < 2; ++nt) {
            int br = nbase + nt*16 + fr;
            bf[nt] = *(const f16x8*)&Bs[cur][br*32 + ((quad ^ (br & 3))*8)];
        }
        #pragma unroll
        for (int mt = 0; mt < 4; ++mt)
            #pragma unroll
            for (int nt = 0; nt < 2; ++nt)
                acc[mt][nt] = __builtin_amdgcn_mfma_f32_16x16x32_f16(
                    af[mt], bf[nt], acc[mt][nt], 0, 0, 0);
        SBAR();
        cur ^= 1;
    }
    #pragma unroll
    for (int mt = 0; mt < 4; ++mt) {
        int sb = s0 + mbase + mt*16 + quad*4;
        #pragma unroll
        for (int nt = 0; nt < 2; ++nt) {
            int r = nbase + nt*16 + fr;
            *(f32x4*)&aff[((size_t)(b*R_ + r))*S_ + sb] = acc[mt][nt];
        }
    }
}

// ============================================================
// K4: per (b,t,r): approx top-8 of aff row, gap-guarded exact fp32 fallback,
//     write top-4 indices
// grid (64 r, 8 t, 8 b)
__global__ __launch_bounds__(256) void k_topk(
    const float* __restrict__ x, const float* __restrict__ trf,
    const float* __restrict__ aff, int* __restrict__ inds)
{
    __shared__ float row[HW_];
    __shared__ float sval[256];
    __shared__ int   sidx[256];
    __shared__ float cval[8];
    __shared__ int   cidx[8];
    __shared__ float eval_[8];
    int r = blockIdx.x, t = blockIdx.y, b = blockIdx.z;
    int tid = threadIdx.x;
    const float* arow = aff + ((size_t)(b*R_ + r))*S_ + t*HW_;
    for (int s = tid; s < HW_; s += 256) row[s] = arow[s];
    __syncthreads();
    for (int pass = 0; pass < 8; ++pass) {
        float best = -INFINITY; int bi = 0;
        for (int s = tid; s < HW_; s += 256) {
            float v = row[s];
            if (v > best) { best = v; bi = s; }
        }
        sval[tid] = best; sidx[tid] = bi;
        __syncthreads();
        for (int off = 128; off > 0; off >>= 1) {
            if (tid < off) {
                float ov = sval[tid+off]; int oi = sidx[tid+off];
                if (ov > sval[tid] || (ov == sval[tid] && oi < sidx[tid])) {
                    sval[tid] = ov; sidx[tid] = oi;
                }
            }
            __syncthreads();
        }
        if (tid == 0) {
            cval[pass] = sval[0]; cidx[pass] = sidx[0];
            row[sidx[0]] = -INFINITY;
        }
        __syncthreads();
    }
    if (cval[3] - cval[4] >= 0.35f) {
        if (tid < K_)
            inds[((b*K_ + tid)*T_ + t)*R_ + r] = cidx[tid];
    } else {
        // exact fp32 recompute of the 8 candidates
        int w = tid >> 6, lane = tid & 63;
        #pragma unroll
        for (int half = 0; half < 2; ++half) {
            int j = w + half*4;
            int cand = cidx[j];
            float sum = 0.f;
            #pragma unroll
            for (int i = 0; i < 8; ++i) {
                int c = lane + i*64;
                sum += trf[((size_t)(b*R_ + r))*C_ + c]
                     * x[((size_t)(b*C_ + c))*S_ + t*HW_ + cand];
            }
            #pragma unroll
            for (int off = 32; off > 0; off >>= 1) sum += __shfl_xor(sum, off);
            if (lane == 0) eval_[j] = sum;
        }
        __syncthreads();
        if (tid == 0) {
            unsigned used = 0;
            for (int k = 0; k < K_; ++k) {
                float bv = -INFINITY; int bj = -1;
                for (int j = 0; j < 8; ++j) {
                    if (used & (1u << j)) continue;
                    float v = eval_[j]; int ii = cidx[j];
                    if (bj < 0 || v > bv || (v == bv && ii < cidx[bj])) {
                        bv = v; bj = j;
                    }
                }
                used |= 1u << bj;
                inds[((b*K_ + k)*T_ + t)*R_ + r] = cidx[bj];
            }
        }
    }
}

// ============================================================
// K5: ptsT[b][p][c] f16 = mean_k x[b,c,t,ind],  p=t*64+r
__global__ __launch_bounds__(256) void k_pointsT(
    const float* __restrict__ x, const int* __restrict__ inds,
    f16* __restrict__ ptsT)
{
    __shared__ float tile[64][65];
    __shared__ int   indl[4][64];
    int c0 = blockIdx.x*64, t = blockIdx.y, b = blockIdx.z;
    int tid = threadIdx.x;
    {
        int k = tid >> 6, r = tid & 63;
        indl[k][r] = inds[((b*K_ + k)*T_ + t)*R_ + r];
    }
    __syncthreads();
    #pragma unroll
    for (int i = 0; i < 16; ++i) {
        int idx = tid + i*256;
        int cl = idx >> 6, r = idx & 63;
        const float* base = x + (size_t)(b*C_ + c0 + cl)*S_ + t*HW_;
        float v = base[indl[0][r]] + base[indl[1][r]] + base[indl[2][r]] + base[indl[3][r]];
        tile[cl][r] = 0.25f*v;
    }
    __syncthreads();
    #pragma unroll
    for (int i = 0; i < 16; ++i) {
        int idx = tid + i*256;
        int rl = idx >> 6, cl = idx & 63;
        ptsT[((size_t)b*P_ + t*64 + rl)*C_ + c0 + cl] = (f16)tile[cl][rl];
    }
}

// ============================================================
// K6: fuse_k via MFMA (gathered B rows via per-lane global addr)
// grid 256 = (bk<<3)|t; tile 128q x 64r; BK=32 dbuf + counted vmcnt + swizzle
// OUTPUT TRANSPOSED: fusekT[bk][p=t*64+r][q] f16 (q contiguous, f16x4 stores)
__global__ __launch_bounds__(256) void k_fuse(
    const f16* __restrict__ xT, const f16* __restrict__ wph,
    const float* __restrict__ wp,
    const float* __restrict__ g2, const float* __restrict__ b2,
    const float* __restrict__ m2, const float* __restrict__ v2,
    f16* __restrict__ fusekT, const int* __restrict__ inds)
{
    __shared__ __align__(16) f16 As[2][128*32];
    __shared__ __align__(16) f16 Bs[2][64*32];
    __shared__ float scq[128], shq[128], wrq[128], wcq[128];
    __shared__ float rowv[64], colv[64];
    int bid = blockIdx.x;
    int t = bid & 7, bk = bid >> 3;
    int b = bk >> 2;
    int tid = threadIdx.x;
    int lane = tid & 63, w = tid >> 6;
    // epilogue constants
    if (tid < 128) {
        float sc = g2[tid] * rsqrtf(v2[tid] + EPSB);
        scq[tid] = sc;
        shq[tid] = b2[tid] - m2[tid]*sc;
        wrq[tid] = wp[tid*514 + 512];
        wcq[tid] = wp[tid*514 + 513];
    } else if (tid < 192) {
        int r = tid - 128;
        int id = inds[bk*T_*R_ + t*R_ + r];
        rowv[r] = (float)(id / 28) * (1.0f/28.0f);
        colv[r] = (float)(id % 28) * (1.0f/28.0f);
    }
    // staging mapping: row = tid>>2 (0..63), slot = (tid&3) ^ (row&3)
    int strow = tid >> 2;
    int slot  = (tid & 3) ^ (strow & 3);
    int ind = inds[bk*T_*R_ + t*R_ + strow];
    const f16* ga = wph + (size_t)strow*C_ + slot*8;                   // q rows (0..63, +64)
    const f16* gb = xT + ((size_t)b*S_ + t*HW_ + ind)*C_ + slot*8;     // gathered r rows
    int mbase = (w & 1)*64, nbase = (w >> 1)*32;
    int fr = lane & 15, quad = lane >> 4;
    f32x4 acc[4][2] = {};
    __syncthreads();   // drain constant-setup loads before counted-vmcnt region
    // prologue stage step 0  (rows 64..127 live at f16 offset 64*32 = 2048)
    gload16(ga,         (f16*)As[0] + tid*8);
    gload16(ga + 64*C_, (f16*)As[0] + 2048 + tid*8);
    gload16(gb,         (f16*)Bs[0] + tid*8);
    ga += 32; gb += 32;
    int cur = 0;
    for (int i = 0; i < 16; ++i) {
        if (i < 15) {
            gload16(ga,         (f16*)As[cur^1] + tid*8);
            gload16(ga + 64*C_, (f16*)As[cur^1] + 2048 + tid*8);
            gload16(gb,         (f16*)Bs[cur^1] + tid*8);
            ga += 32; gb += 32;
            WAITV(3);
        } else {
            WAITV(0);
        }
        SCHB(); SBAR();
        f16x8 af[4], bf[2];
        #pragma unroll
        for (int mt = 0; mt < 4; ++mt) {
            int ar = mbase + mt*16 + fr;
            af[mt] = *(const f16x8*)&As[cur][ar*32 + ((quad ^ (ar & 3))*8)];
        }
        #pragma unroll
        for (int nt = 0; nt < 2; ++nt) {
            int br = nbase + nt*16 + fr;
            bf[nt] = *(const f16x8*)&Bs[cur][br*32 + ((quad ^ (br & 3))*8)];
        }
        #pragma unroll
        for (int mt = 0; mt < 4; ++mt)
            #pragma unroll
            for (int nt = 0; nt < 2; ++nt)
                acc[mt][nt] = __builtin_amdgcn_mfma_f32_16x16x32_f16(
                    af[mt], bf[nt], acc[mt][nt], 0, 0, 0);
        SBAR();
        cur ^= 1;
    }
    #pragma unroll
    for (int mt = 0; mt < 4; ++mt) {
        int qb = mbase + mt*16 + quad*4;
        #pragma unroll
        for (int nt = 0; nt < 2; ++nt) {
            int r = nbase + nt*16 + fr;
            f16x4 h;
            #pragma unroll
            for (int i = 0; i < 4; ++i) {
                int q = qb + i;
                float v = acc[mt][nt][i] + wrq[q]*rowv[r] + wcq[q]*colv[r];
                h[i] = (f16)(v*scq[q] + shq[q]);
            }
            *(f16x4*)&fusekT[((size_t)bk*P_ + t*R_ + r)*CQ_ + qb] = h;
        }
    }
}

// ============================================================
// K7: fuseT[b][p][q] f16 = max_k fusekT[b*4+k][p][q]
// grid 256: 65536 threads x f16x8
__global__ __launch_bounds__(256) void k_maxk(
    const f16* __restrict__ fusekT, f16* __restrict__ fuseT)
{
    int idx8 = (blockIdx.x*256 + threadIdx.x)*8;   // 524288 elems
    int b = idx8 >> 16;
    int pq = idx8 & 65535;
    const f16* base = fusekT + (size_t)(b*4)*65536 + pq;
    f16x8 v0 = *(const f16x8*)base;
    #pragma unroll
    for (int k = 1; k < K_; ++k) {
        f16x8 vk = *(const f16x8*)(base + (size_t)k*65536);
        #pragma unroll
        for (int j = 0; j < 8; ++j)
            v0[j] = (float)vk[j] > (float)v0[j] ? vk[j] : v0[j];
    }
    *(f16x8*)&fuseT[(size_t)b*65536 + pq] = v0;
}

// ============================================================
// K8: temporal conv via MFMA + bn3 + relu -> tc f16 [b][c][p]
// grid (4 p-tiles, 4 co-tiles, 8 b); tile 128co x 128p, K=384 over 6 steps
__global__ __launch_bounds__(256) void k_conv(
    const f16* __restrict__ wth,
    const float* __restrict__ g3, const float* __restrict__ b3,
    const float* __restrict__ m3, const float* __restrict__ v3,
    const f16* __restrict__ fuseT, f16* __restrict__ tc)
{
    __shared__ __align__(16) f16 As[128*64];   // p rows
    __shared__ __align__(16) f16 Bs[128*64];   // co rows
    int p0 = blockIdx.x*128, c0 = blockIdx.y*128, b = blockIdx.z;
    int tid = threadIdx.x;
    int lane = tid & 63, w = tid >> 6;
    int lrow = lane >> 3;
    int swzc = ((lane & 7) ^ lrow) * 8;
    int mrow = (w & 1)*64, nrow = (w >> 1)*64;
    int fr = lane & 15, quad = lane >> 4;
    int sw = fr & 7;
    f32x4 acc[4][4] = {};
    for (int step = 0; step < 6; ++step) {
        int dt = step >> 1, h = step & 1;
        int shift = (dt - 1)*64;
        #pragma unroll
        for (int j = 0; j < 4; ++j) {
            int rb = w*32 + j*8;
            int pg = p0 + rb + shift;          // 8-row group base in p'
            if (pg >= 0 && pg < P_)
                gload16(fuseT + ((size_t)b*P_ + pg + lrow)*CQ_ + h*64 + swzc,
                        &As[rb*64]);
            else
                *(f32x4*)((char*)&As[rb*64] + lane*16) = (f32x4){0.f,0.f,0.f,0.f};
        }
        #pragma unroll
        for (int j = 0; j < 4; ++j) {
            int rb = w*32 + j*8;
            gload16(wth + (size_t)(c0 + rb + lrow)*384 + dt*128 + h*64 + swzc,
                    &Bs[rb*64]);
        }
        __syncthreads();
        #pragma unroll
        for (int kk = 0; kk < 2; ++kk) {
            int ch = ((kk*4 + quad) ^ sw) * 8;
            f16x8 af[4], bf[4];
            #pragma unroll
            for (int mt = 0; mt < 4; ++mt)
                af[mt] = *(const f16x8*)&As[(mrow + mt*16 + fr)*64 + ch];
            #pragma unroll
            for (int nt = 0; nt < 4; ++nt)
                bf[nt] = *(const f16x8*)&Bs[(nrow + nt*16 + fr)*64 + ch];
            #pragma unroll
            for (int mt = 0; mt < 4; ++mt)
                #pragma unroll
                for (int nt = 0; nt < 4; ++nt)
                    acc[mt][nt] = __builtin_amdgcn_mfma_f32_16x16x32_f16(
                        af[mt], bf[nt], acc[mt][nt], 0, 0, 0);
        }
        __syncthreads();
    }
    #pragma unroll
    for (int nt = 0; nt < 4; ++nt) {
        int co = c0 + nrow + nt*16 + fr;
        float sc = g3[co] * rsqrtf(v3[co] + EPSB);
        float sh = b3[co] - m3[co]*sc;
        #pragma unroll
        for (int mt = 0; mt < 4; ++mt) {
            int p = p0 + mrow + mt*16 + quad*4;
            f16x4 hv;
            #pragma unroll
            for (int i = 0; i < 4; ++i)
                hv[i] = (f16)fmaxf(acc[mt][nt][i]*sc + sh, 0.f);
            *(f16x4*)&tc[((size_t)(b*C_ + co))*P_ + p] = hv;
        }
    }
}

// ============================================================
// K9: fused L-GEMM + row softmax (BK=32 dbuf + counted vmcnt):
//   L[s][p] = sum_c xT[s][c]*ptsT[p][c]  (full p=512 per block in registers)
//   W f16 = exp(L - rowmax), Dinv = 1/rowsum
// grid (cnt, 1, 8); 512 threads = 8 waves (2 s-halves x 4 p-quarters)
__global__ __launch_bounds__(512, 2) void k_attnW(
    const f16* __restrict__ xT, const f16* __restrict__ ptsT,
    f16* __restrict__ W, float* __restrict__ Dinv, int st, int NCHb)
{
    __shared__ __align__(16) f16 As[2][128*32];   // s rows (2 x 8 KB)
    __shared__ __align__(16) f16 Bs[2][512*32];   // p rows (2 x 32 KB)
    int lt = blockIdx.x; int b = blockIdx.z;
    int s0 = (st + lt)*128;
    int tid = threadIdx.x;
    int lane = tid & 63, w = tid >> 6;
    int wr = w & 1, wc = w >> 1;
    int strow = tid >> 2;                   // 0..127
    int slot  = (tid & 3) ^ (strow & 3);
    const f16* ga = xT   + ((size_t)b*S_ + s0 + strow)*C_ + slot*8;
    const f16* gb = ptsT + ((size_t)b*P_ + strow)*C_ + slot*8;     // +j*128 rows
    int fr = lane & 15, quad = lane >> 4;
    f32x4 acc[8][4] = {};                      // [nt over p][mt over s]
    // prologue stage step 0
    gload16(ga, (f16*)As[0] + tid*8);
    #pragma unroll
    for (int j = 0; j < 4; ++j)
        gload16(gb + (size_t)j*128*C_, (f16*)Bs[0] + j*4096 + tid*8);
    ga += 32; gb += 32;
    int cur = 0;
    for (int i = 0; i < 16; ++i) {
        if (i < 15) {
            gload16(ga, (f16*)As[cur^1] + tid*8);
            #pragma unroll
            for (int j = 0; j < 4; ++j)
                gload16(gb + (size_t)j*128*C_, (f16*)Bs[cur^1] + j*4096 + tid*8);
            ga += 32; gb += 32;
            WAITV(5);
        } else {
            WAITV(0);
        }
        SCHB(); SBAR();
        f16x8 af[4], bf[8];
        #pragma unroll
        for (int mt = 0; mt < 4; ++mt) {
            int ar = wr*64 + mt*16 + fr;
            af[mt] = *(const f16x8*)&As[cur][ar*32 + ((quad ^ (ar & 3))*8)];
        }
        #pragma unroll
        for (int nt = 0; nt < 8; ++nt) {
            int br = wc*128 + nt*16 + fr;
            bf[nt] = *(const f16x8*)&Bs[cur][br*32 + ((quad ^ (br & 3))*8)];
        }
        // swapped: C col = s (fr), C row = p (quad*4+i)
        #pragma unroll
        for (int nt = 0; nt < 8; ++nt)
            #pragma unroll
            for (int mt = 0; mt < 4; ++mt)
                acc[nt][mt] = __builtin_amdgcn_mfma_f32_16x16x32_f16(
                    bf[nt], af[mt], acc[nt][mt], 0, 0, 0);
        SBAR();
        cur ^= 1;
    }
    // ---- in-register softmax over p=512 per s-row (red aliased onto As) ----
    float (*red)[4] = (float (*)[4])As;
    float M[4];
    #pragma unroll
    for (int mt = 0; mt < 4; ++mt) {
        float m = -INFINITY;
        #pragma unroll
        for (int nt = 0; nt < 8; ++nt)
            #pragma unroll
            for (int i = 0; i < 4; ++i)
                m = fmaxf(m, acc[nt][mt][i]);
        m = fmaxf(m, __shfl_xor(m, 16));
        m = fmaxf(m, __shfl_xor(m, 32));
        if (quad == 0) red[wr*64 + mt*16 + fr][wc] = m;
    }
    __syncthreads();
    #pragma unroll
    for (int mt = 0; mt < 4; ++mt) {
        int srow = wr*64 + mt*16 + fr;
        M[mt] = fmaxf(fmaxf(red[srow][0], red[srow][1]),
                      fmaxf(red[srow][2], red[srow][3]));
    }
    __syncthreads();
    #pragma unroll
    for (int mt = 0; mt < 4; ++mt) {
        float s = 0.f;
        #pragma unroll
        for (int nt = 0; nt < 8; ++nt)
            #pragma unroll
            for (int i = 0; i < 4; ++i) {
                float e = __expf(acc[nt][mt][i] - M[mt]);
                acc[nt][mt][i] = e;
                s += e;
            }
        s += __shfl_xor(s, 16);
        s += __shfl_xor(s, 32);
        if (quad == 0) red[wr*64 + mt*16 + fr][wc] = s;
    }
    __syncthreads();
    size_t wbase = (size_t)(b*NCHb + lt)*128*(size_t)P_;
    #pragma unroll
    for (int mt = 0; mt < 4; ++mt) {
        int srow = wr*64 + mt*16 + fr;
        float tot = (red[srow][0] + red[srow][1]) + (red[srow][2] + red[srow][3]);
        if (wc == 0 && quad == 0)
            Dinv[(size_t)b*S_ + s0 + srow] = 1.0f/tot;
        #pragma unroll
        for (int nt = 0; nt < 8; ++nt) {
            f16x4 h;
            #pragma unroll
            for (int i = 0; i < 4; ++i) h[i] = (f16)acc[nt][mt][i];
            *(f16x4*)&W[wbase + (size_t)srow*P_ + wc*128 + nt*16 + quad*4] = h;
        }
    }
}

// ============================================================
// K11: out[b][c][s] = x + Dinv[s] * sum_p tc[b][c][p] * W[row(s)][p]
// grid (cnt, 4, 8); BK=32 dbuf + counted vmcnt, 32 KB LDS -> 5 blocks/CU
__global__ __launch_bounds__(256) void k_gemmP(
    const f16* __restrict__ tc, const f16* __restrict__ W,
    const float* __restrict__ Dinv, const float* __restrict__ x,
    float* __restrict__ out, int st, int NCHb)
{
    __shared__ __align__(16) f16 As[2][128*32];
    __shared__ __align__(16) f16 Bs[2][128*32];
    int lt = blockIdx.x; int b = blockIdx.z;
    int s0 = (st + lt)*128, c0t = blockIdx.y*128;
    int tid = threadIdx.x;
    int lane = tid & 63, w = tid >> 6;
    int strow = tid >> 2;                   // 0..63
    int slot  = (tid & 3) ^ (strow & 3);
    const f16* ga = tc + ((size_t)(b*C_) + c0t + strow)*P_ + slot*8;
    const f16* gb = W  + ((size_t)(b*NCHb + lt)*128 + strow)*P_ + slot*8;
    int mrow = (w & 1)*64, nrow = (w >> 1)*64;
    int fr = lane & 15, quad = lane >> 4;
    f32x4 acc[4][4] = {};
    // prologue (rows 64..127 at f16 offset 64*32 = 2048)
    gload16(ga,         (f16*)As[0] + tid*8);
    gload16(ga + 64*P_, (f16*)As[0] + 2048 + tid*8);
    gload16(gb,         (f16*)Bs[0] + tid*8);
    gload16(gb + 64*P_, (f16*)Bs[0] + 2048 + tid*8);
    ga += 32; gb += 32;
    int cur = 0;
    for (int i = 0; i < 16; ++i) {
        if (i < 15) {
            gload16(ga,         (f16*)As[cur^1] + tid*8);
            gload16(ga + 64*P_, (f16*)As[cur^1] + 2048 + tid*8);
            gload16(gb,         (f16*)Bs[cur^1] + tid*8);
            gload16(gb + 64*P_, (f16*)Bs[cur^1] + 2048 + tid*8);
            ga += 32; gb += 32;
            WAITV(4);
        } else {
            WAITV(0);
        }
        SCHB(); SBAR();
        f16x8 af[4], bf[4];
        #pragma unroll
        for (int mt = 0; mt < 4; ++mt) {
            int ar = mrow + mt*16 + fr;
            af[mt] = *(const f16x8*)&As[cur][ar*32 + ((quad ^ (ar & 3))*8)];
        }
        #pragma unroll
        for (int nt = 0; nt < 4; ++nt) {
            int br = nrow + nt*16 + fr;
            bf[nt] = *(const f16x8*)&Bs[cur][br*32 + ((quad ^ (br & 3))*8)];
        }
        // swapped: C row = s (from bf), C col = c (from af)
        #pragma unroll
        for (int nt = 0; nt < 4; ++nt)
            #pragma unroll
            for (int mt = 0; mt < 4; ++mt)
                acc[nt][mt] = __builtin_amdgcn_mfma_f32_16x16x32_f16(
                    bf[nt], af[mt], acc[nt][mt], 0, 0, 0);
        SBAR();
        cur ^= 1;
    }
    #pragma unroll
    for (int nt = 0; nt < 4; ++nt) {
        int s = s0 + nrow + nt*16 + quad*4;
        f32x4 dv = *(const f32x4*)&Dinv[(size_t)b*S_ + s];
        #pragma unroll
        for (int mt = 0; mt < 4; ++mt) {
            int c = c0t + mrow + mt*16 + fr;
            size_t o = ((size_t)(b*C_ + c))*S_ + s;
            f32x4 xv = *(const f32x4*)&x[o];
            f32x4 res = xv + acc[nt][mt]*dv;
            *(f32x4*)&out[o] = res;
        }
    }
}

// ============================================================
extern "C" void kernel_launch(void* const* d_in, const int* in_sizes, int n_in,
                              void* d_out, int out_size, void* d_ws, size_t ws_size,
                              hipStream_t stream) {
    const float* x   = (const float*)d_in[0];
    const float* wrd = (const float*)d_in[1];
    const float* g1  = (const float*)d_in[2];
    const float* v1  = (const float*)d_in[5];
    const float* wp  = (const float*)d_in[6];
    const float* g2  = (const float*)d_in[7];
    const float* b2  = (const float*)d_in[8];
    const float* m2  = (const float*)d_in[9];
    const float* v2  = (const float*)d_in[10];
    const float* wt  = (const float*)d_in[11];
    const float* g3  = (const float*)d_in[12];
    const float* b3  = (const float*)d_in[13];
    const float* m3  = (const float*)d_in[14];
    const float* v3  = (const float*)d_in[15];
    char*  wsb = (char*)d_ws;
    float* out = (float*)d_out;

    f16*   ptsT  = (f16*)  (wsb + OB_PTST);
    f16*   tc    = (f16*)  (wsb + OB_TC);
    float* Dinv  = (float*)(wsb + OB_D);
    f16*   trh   = (f16*)  (wsb + OB_TRH);
    float* trf   = (float*)(wsb + OB_TRF);
    int*   inds  = (int*)  (wsb + OB_INDS);
    f16*   wrh   = (f16*)  (wsb + OB_WRH);
    f16*   wph   = (f16*)  (wsb + OB_WPH);
    f16*   wth   = (f16*)  (wsb + OB_WTH);
    f16*   xT    = (f16*)  (wsb + OB_XT);
    float* tpa   = (float*)(wsb + T_TPA);
    float* aff   = (float*)(wsb + T_AFF);
    f16*   fusekT= (f16*)  (wsb + T_FUSEK);
    f16*   fuseT = (f16*)  (wsb + T_FUSE);

    // s-tile chunking (deterministic from ws_size -> graph-safe)
    const size_t PER_TILE = 1048576ull;   // W f16 per s-tile, all 8 batches
    size_t avail = ws_size > CHB ? ws_size - CHB : 0;
    int NCH = (int)(avail / PER_TILE);
    if (NCH < 1) NCH = 1;
    if (NCH > 49) NCH = 49;
    int nchunks = (49 + NCH - 1)/NCH;
    int NCHb = (49 + nchunks - 1)/nchunks;
    f16* W = (f16*)(wsb + CHB);

    k_prep<<<1152, 256, 0, stream>>>(wrd, wp, wt, wrh, wph, wth);
    k_xpose<<<dim3(98, 8, 8), 256, 0, stream>>>(x, xT);
    k_templ<<<dim3(7, 8), 256, 0, stream>>>(xT, wrh, tpa);
    k_targmax<<<512, 256, 0, stream>>>(x, wrd, g1, v1, tpa, trf, trh);
    k_affin<<<dim3(49, 8), 256, 0, stream>>>(xT, trh, aff);
    k_topk<<<dim3(R_, T_, B_), 256, 0, stream>>>(x, trf, aff, inds);
    k_pointsT<<<dim3(8, 8, 8), 256, 0, stream>>>(x, inds, ptsT);
    k_fuse<<<256, 256, 0, stream>>>(xT, wph, wp, g2, b2, m2, v2, fusekT, inds);
    k_maxk<<<256, 256, 0, stream>>>(fusekT, fuseT);
    k_conv<<<dim3(4, 4, 8), 256, 0, stream>>>(wth, g3, b3, m3, v3, fuseT, tc);

    for (int st = 0; st < 49; st += NCHb) {
        int cnt = (49 - st) < NCHb ? (49 - st) : NCHb;
        k_attnW<<<dim3(cnt, 1, 8), 512, 0, stream>>>(xT, ptsT, W, Dinv, st, NCHb);
        k_gemmP<<<dim3(cnt, 4, 8), 256, 0, stream>>>(tc, W, Dinv, x, out, st, NCHb);
    }
}

// Round 8
// 477.531 us; speedup vs baseline: 1.0569x; 1.0569x over previous
//
#include <hip/hip_runtime.h>

#define EPSB 1e-5f

// problem sizes
#define B_   8
#define C_   512
#define T_   8
#define HW_  784
#define S_   6272     // T*HW
#define R_   64
#define CQ_  128
#define K_   4
#define P_   512      // T*R

typedef _Float16 f16;
typedef __attribute__((ext_vector_type(8))) _Float16 f16x8;
typedef __attribute__((ext_vector_type(4))) _Float16 f16x4;
typedef __attribute__((ext_vector_type(4))) float    f32x4;

// ---- workspace byte offsets ----
#define OB_PTST  0ull                       // f16 [8][512][512]
#define OB_TC    4194304ull                 // f16 [8][512][512]
#define OB_D     8388608ull                 // f32 [8][6272]
#define OB_TRH   8589312ull                 // f16 [512][512]   (b*64+r rows)
#define OB_TRF   9113600ull                 // f32 [512][512]
#define OB_INDS  10162176ull                // int [8][4][8][64]
#define OB_WRH   10227712ull                // f16 [64][512]
#define OB_WPH   10293248ull                // f16 [128][512]  (w_proj cols 0..511)
#define OB_WTH   10424320ull                // f16 [512][3][128] (w_t repacked)
#define OB_XT    10817536ull                // f16 [8][6272][512]  51,380,224
// transients (region reused over time; all dead before the gemm chunks)
#define T_TPA    62197760ull                // f32 [512][784]    1,605,632  (dead after targmax)
#define T_AFF    63803392ull                // f32 [512][6272]  12,845,056  (dead after topk)
#define T_FUSEK  62197760ull                // f16 [32][512][128] (written after tpa dead)
#define T_FUSE   66392064ull                // f16 [8][512][128]  (fuseT, p-major)
#define CHB      62197760ull                // chunk region base (after conv everything above is dead)

#define SBAR()  __builtin_amdgcn_s_barrier()
#define SCHB()  __builtin_amdgcn_sched_barrier(0)
#define WAITV(N) asm volatile("s_waitcnt vmcnt(" #N ")" ::: "memory")

__device__ __forceinline__ void gload16(const void* g, void* l) {
    __builtin_amdgcn_global_load_lds(
        (const __attribute__((address_space(1))) unsigned int*)g,
        (__attribute__((address_space(3))) unsigned int*)l, 16, 0, 0);
}

// ============================================================
// P0: convert w_reduce -> f16 (32768), w_proj cols 0..511 -> f16 (65536),
//     w_t repack -> wth[co][dt][ci] f16 (196608)
__global__ __launch_bounds__(256) void k_prep(
    const float* __restrict__ wr, const float* __restrict__ wp,
    const float* __restrict__ wt,
    f16* __restrict__ wrh, f16* __restrict__ wph, f16* __restrict__ wth)
{
    int i = blockIdx.x*256 + threadIdx.x;   // 294912
    if (i < 32768) {
        wrh[i] = (f16)wr[i];
    } else if (i < 98304) {
        int j = i - 32768;
        int q = j >> 9, c = j & 511;
        wph[j] = (f16)wp[q*514 + c];
    } else {
        int j = i - 98304;                  // 196608 = 512*384
        int co = j / 384;
        int rem = j - co*384;
        int dt = rem >> 7, ci = rem & 127;
        wth[j] = (f16)wt[(size_t)(co*CQ_ + ci)*3 + dt];
    }
}

// ============================================================
// K0: transpose+convert x[b][c][s] f32 -> xT[b][s][c] f16
__global__ __launch_bounds__(256) void k_xpose(
    const float* __restrict__ x, f16* __restrict__ xT)
{
    __shared__ float tile[64][65];
    int s0 = blockIdx.x*64, c0 = blockIdx.y*64, b = blockIdx.z;
    int tid = threadIdx.x;
    #pragma unroll
    for (int i = 0; i < 4; ++i) {
        int idx = tid + i*256;
        int cl = idx >> 4, s4 = (idx & 15)*4;
        f32x4 v = *(const f32x4*)&x[((size_t)(b*C_ + c0+cl))*S_ + s0 + s4];
        tile[cl][s4] = v.x; tile[cl][s4+1] = v.y;
        tile[cl][s4+2] = v.z; tile[cl][s4+3] = v.w;
    }
    __syncthreads();
    #pragma unroll
    for (int i = 0; i < 4; ++i) {
        int idx = tid + i*256;
        int sl = idx >> 4, c4 = (idx & 15)*4;
        f16x4 h;
        h[0] = (f16)tile[c4+0][sl]; h[1] = (f16)tile[c4+1][sl];
        h[2] = (f16)tile[c4+2][sl]; h[3] = (f16)tile[c4+3][sl];
        *(f16x4*)&xT[((size_t)(b*S_ + s0+sl))*C_ + c0 + c4] = h;
    }
}

// ============================================================
// K1: template dots via MFMA: tpa[b*64+r][s] = sum_c wrh[r][c]*xT[b][s][c]
// grid (7, 8): tile 128s x 64r, BK=64, dbuf + counted vmcnt
__global__ __launch_bounds__(256) void k_templ(
    const f16* __restrict__ xT, const f16* __restrict__ wrh,
    float* __restrict__ tpa)
{
    __shared__ __align__(16) f16 As[2][128*64];
    __shared__ __align__(16) f16 Bs[2][64*64];
    int b = blockIdx.y; int s0 = blockIdx.x*128;
    int tid = threadIdx.x;
    int lane = tid & 63, w = tid >> 6;
    int lrow = lane >> 3;
    int swzc = ((lane & 7) ^ lrow) * 8;
    const f16* ga = xT  + ((size_t)b*S_ + s0 + w*32 + lrow)*C_ + swzc;
    const f16* gb = wrh + (size_t)(w*16 + lrow)*C_ + swzc;
    int mbase = (w & 1)*64, nbase = (w >> 1)*32;
    int fr = lane & 15, quad = lane >> 4;
    int sw = fr & 7;
    f32x4 acc[4][2] = {};
    #pragma unroll
    for (int j = 0; j < 4; ++j)
        gload16(ga + j*8*C_, &As[0][(w*32 + j*8)*64]);
    #pragma unroll
    for (int j = 0; j < 2; ++j)
        gload16(gb + j*8*C_, &Bs[0][(w*16 + j*8)*64]);
    ga += 64; gb += 64;
    int cur = 0;
    for (int i = 0; i < 8; ++i) {
        if (i < 7) {
            #pragma unroll
            for (int j = 0; j < 4; ++j)
                gload16(ga + j*8*C_, &As[cur^1][(w*32 + j*8)*64]);
            #pragma unroll
            for (int j = 0; j < 2; ++j)
                gload16(gb + j*8*C_, &Bs[cur^1][(w*16 + j*8)*64]);
            ga += 64; gb += 64;
            WAITV(6);
        } else {
            WAITV(0);
        }
        SCHB(); SBAR();
        #pragma unroll
        for (int kk = 0; kk < 2; ++kk) {
            int ch = ((kk*4 + quad) ^ sw) * 8;
            f16x8 af[4], bf[2];
            #pragma unroll
            for (int mt = 0; mt < 4; ++mt)
                af[mt] = *(const f16x8*)&As[cur][(mbase + mt*16 + fr)*64 + ch];
            #pragma unroll
            for (int nt = 0; nt < 2; ++nt)
                bf[nt] = *(const f16x8*)&Bs[cur][(nbase + nt*16 + fr)*64 + ch];
            #pragma unroll
            for (int mt = 0; mt < 4; ++mt)
                #pragma unroll
                for (int nt = 0; nt < 2; ++nt)
                    acc[mt][nt] = __builtin_amdgcn_mfma_f32_16x16x32_f16(
                        af[mt], bf[nt], acc[mt][nt], 0, 0, 0);
        }
        SBAR();
        cur ^= 1;
    }
    #pragma unroll
    for (int mt = 0; mt < 4; ++mt) {
        int sb = s0 + mbase + mt*16 + quad*4;
        if (sb < HW_) {
            #pragma unroll
            for (int nt = 0; nt < 2; ++nt) {
                int r = nbase + nt*16 + fr;
                *(f32x4*)&tpa[((size_t)(b*R_ + r))*HW_ + sb] = acc[mt][nt];
            }
        }
    }
}

// ============================================================
// K2: per (b,r): approx argmax of tpa*sc, gap-guarded exact fp32 fallback,
//     then gather tr row (f32 + f16)
// grid 512 = b*64+r
__global__ __launch_bounds__(256) void k_targmax(
    const float* __restrict__ x, const float* __restrict__ wr_g,
    const float* __restrict__ g1, const float* __restrict__ v1,
    const float* __restrict__ tpa,
    float* __restrict__ trf, f16* __restrict__ trh)
{
    __shared__ float row[HW_];
    __shared__ float sval[256];
    __shared__ int   sidx[256];
    __shared__ float cval[4];
    __shared__ int   cidx[4];
    __shared__ float eval_[4];
    __shared__ int   bestind;
    int bid = blockIdx.x;
    int b = bid >> 6, r = bid & 63;
    int tid = threadIdx.x;
    float sc = g1[r] * rsqrtf(v1[r] + EPSB);
    const float* tprow = tpa + (size_t)bid*HW_;
    for (int s = tid; s < HW_; s += 256) row[s] = tprow[s]*sc;
    __syncthreads();
    for (int pass = 0; pass < 4; ++pass) {
        float best = -INFINITY; int bi = 0;
        for (int s = tid; s < HW_; s += 256) {
            float v = row[s];
            if (v > best) { best = v; bi = s; }
        }
        sval[tid] = best; sidx[tid] = bi;
        __syncthreads();
        for (int off = 128; off > 0; off >>= 1) {
            if (tid < off) {
                float ov = sval[tid+off]; int oi = sidx[tid+off];
                if (ov > sval[tid] || (ov == sval[tid] && oi < sidx[tid])) {
                    sval[tid] = ov; sidx[tid] = oi;
                }
            }
            __syncthreads();
        }
        if (tid == 0) {
            cval[pass] = sval[0]; cidx[pass] = sidx[0];
            row[sidx[0]] = -INFINITY;
        }
        __syncthreads();
    }
    float thr = 0.05f * fabsf(sc);
    if (cval[0] - cval[1] >= thr) {
        if (tid == 0) bestind = cidx[0];
    } else {
        // exact fp32 recompute of the 4 candidates
        int w = tid >> 6, lane = tid & 63;
        int cand = cidx[w];
        float sum = 0.f;
        #pragma unroll
        for (int i = 0; i < 8; ++i) {
            int c = lane + i*64;
            sum += wr_g[r*C_ + c] * x[((size_t)(b*C_ + c))*S_ + cand];
        }
        #pragma unroll
        for (int off = 32; off > 0; off >>= 1) sum += __shfl_xor(sum, off);
        if (lane == 0) eval_[w] = sum*sc;
        __syncthreads();
        if (tid == 0) {
            float bv = eval_[0]; int bi2 = cidx[0];
            for (int j = 1; j < 4; ++j) {
                float v = eval_[j]; int ii = cidx[j];
                if (v > bv || (v == bv && ii < bi2)) { bv = v; bi2 = ii; }
            }
            bestind = bi2;
        }
    }
    __syncthreads();
    int ind = bestind;
    for (int c = tid; c < C_; c += 256) {
        float v = x[((size_t)(b*C_ + c))*S_ + ind];
        trf[(size_t)bid*C_ + c] = v;
        trh[(size_t)bid*C_ + c] = (f16)v;
    }
}

// ============================================================
// K3: affinity via MFMA: aff[b*64+r][s] = sum_c trh[b*64+r][c]*xT[b][s][c]
// grid (49, 8): tile 128s x 64r, BK=64, dbuf + counted vmcnt
__global__ __launch_bounds__(256) void k_affin(
    const f16* __restrict__ xT, const f16* __restrict__ trh,
    float* __restrict__ aff)
{
    __shared__ __align__(16) f16 As[2][128*64];
    __shared__ __align__(16) f16 Bs[2][64*64];
    int b = blockIdx.y; int s0 = blockIdx.x*128;
    int tid = threadIdx.x;
    int lane = tid & 63, w = tid >> 6;
    int lrow = lane >> 3;
    int swzc = ((lane & 7) ^ lrow) * 8;
    const f16* ga = xT  + ((size_t)b*S_ + s0 + w*32 + lrow)*C_ + swzc;
    const f16* gb = trh + ((size_t)(b*R_) + w*16 + lrow)*C_ + swzc;
    int mbase = (w & 1)*64, nbase = (w >> 1)*32;
    int fr = lane & 15, quad = lane >> 4;
    int sw = fr & 7;
    f32x4 acc[4][2] = {};
    #pragma unroll
    for (int j = 0; j < 4; ++j)
        gload16(ga + j*8*C_, &As[0][(w*32 + j*8)*64]);
    #pragma unroll
    for (int j = 0; j < 2; ++j)
        gload16(gb + j*8*C_, &Bs[0][(w*16 + j*8)*64]);
    ga += 64; gb += 64;
    int cur = 0;
    for (int i = 0; i < 8; ++i) {
        if (i < 7) {
            #pragma unroll
            for (int j = 0; j < 4; ++j)
                gload16(ga + j*8*C_, &As[cur^1][(w*32 + j*8)*64]);
            #pragma unroll
            for (int j = 0; j < 2; ++j)
                gload16(gb + j*8*C_, &Bs[cur^1][(w*16 + j*8)*64]);
            ga += 64; gb += 64;
            WAITV(6);
        } else {
            WAITV(0);
        }
        SCHB(); SBAR();
        #pragma unroll
        for (int kk = 0; kk < 2; ++kk) {
            int ch = ((kk*4 + quad) ^ sw) * 8;
            f16x8 af[4], bf[2];
            #pragma unroll
            for (int mt = 0; mt < 4; ++mt)
                af[mt] = *(const f16x8*)&As[cur][(mbase + mt*16 + fr)*64 + ch];
            #pragma unroll
            for (int nt = 0; nt < 2; ++nt)
                bf[nt] = *(const f16x8*)&Bs[cur][(nbase + nt*16 + fr)*64 + ch];
            #pragma unroll
            for (int mt = 0; mt < 4; ++mt)
                #pragma unroll
                for (int nt = 0; nt < 2; ++nt)
                    acc[mt][nt] = __builtin_amdgcn_mfma_f32_16x16x32_f16(
                        af[mt], bf[nt], acc[mt][nt], 0, 0, 0);
        }
        SBAR();
        cur ^= 1;
    }
    #pragma unroll
    for (int mt = 0; mt < 4; ++mt) {
        int sb = s0 + mbase + mt*16 + quad*4;
        #pragma unroll
        for (int nt = 0; nt < 2; ++nt) {
            int r = nbase + nt*16 + fr;
            *(f32x4*)&aff[((size_t)(b*R_ + r))*S_ + sb] = acc[mt][nt];
        }
    }
}

// ============================================================
// K4: per (b,t,r): approx top-8 of aff row, gap-guarded exact fp32 fallback,
//     write top-4 indices
// grid (64 r, 8 t, 8 b)
__global__ __launch_bounds__(256) void k_topk(
    const float* __restrict__ x, const float* __restrict__ trf,
    const float* __restrict__ aff, int* __restrict__ inds)
{
    __shared__ float row[HW_];
    __shared__ float sval[256];
    __shared__ int   sidx[256];
    __shared__ float cval[8];
    __shared__ int   cidx[8];
    __shared__ float eval_[8];
    int r = blockIdx.x, t = blockIdx.y, b = blockIdx.z;
    int tid = threadIdx.x;
    const float* arow = aff + ((size_t)(b*R_ + r))*S_ + t*HW_;
    for (int s = tid; s < HW_; s += 256) row[s] = arow[s];
    __syncthreads();
    for (int pass = 0; pass < 8; ++pass) {
        float best = -INFINITY; int bi = 0;
        for (int s = tid; s < HW_; s += 256) {
            float v = row[s];
            if (v > best) { best = v; bi = s; }
        }
        sval[tid] = best; sidx[tid] = bi;
        __syncthreads();
        for (int off = 128; off > 0; off >>= 1) {
            if (tid < off) {
                float ov = sval[tid+off]; int oi = sidx[tid+off];
                if (ov > sval[tid] || (ov == sval[tid] && oi < sidx[tid])) {
                    sval[tid] = ov; sidx[tid] = oi;
                }
            }
            __syncthreads();
        }
        if (tid == 0) {
            cval[pass] = sval[0]; cidx[pass] = sidx[0];
            row[sidx[0]] = -INFINITY;
        }
        __syncthreads();
    }
    if (cval[3] - cval[4] >= 0.35f) {
        if (tid < K_)
            inds[((b*K_ + tid)*T_ + t)*R_ + r] = cidx[tid];
    } else {
        // exact fp32 recompute of the 8 candidates
        int w = tid >> 6, lane = tid & 63;
        #pragma unroll
        for (int half = 0; half < 2; ++half) {
            int j = w + half*4;
            int cand = cidx[j];
            float sum = 0.f;
            #pragma unroll
            for (int i = 0; i < 8; ++i) {
                int c = lane + i*64;
                sum += trf[((size_t)(b*R_ + r))*C_ + c]
                     * x[((size_t)(b*C_ + c))*S_ + t*HW_ + cand];
            }
            #pragma unroll
            for (int off = 32; off > 0; off >>= 1) sum += __shfl_xor(sum, off);
            if (lane == 0) eval_[j] = sum;
        }
        __syncthreads();
        if (tid == 0) {
            unsigned used = 0;
            for (int k = 0; k < K_; ++k) {
                float bv = -INFINITY; int bj = -1;
                for (int j = 0; j < 8; ++j) {
                    if (used & (1u << j)) continue;
                    float v = eval_[j]; int ii = cidx[j];
                    if (bj < 0 || v > bv || (v == bv && ii < cidx[bj])) {
                        bv = v; bj = j;
                    }
                }
                used |= 1u << bj;
                inds[((b*K_ + k)*T_ + t)*R_ + r] = cidx[bj];
            }
        }
    }
}

// ============================================================
// K5: ptsT[b][p][c] f16 = mean_k x[b,c,t,ind],  p=t*64+r
__global__ __launch_bounds__(256) void k_pointsT(
    const float* __restrict__ x, const int* __restrict__ inds,
    f16* __restrict__ ptsT)
{
    __shared__ float tile[64][65];
    __shared__ int   indl[4][64];
    int c0 = blockIdx.x*64, t = blockIdx.y, b = blockIdx.z;
    int tid = threadIdx.x;
    {
        int k = tid >> 6, r = tid & 63;
        indl[k][r] = inds[((b*K_ + k)*T_ + t)*R_ + r];
    }
    __syncthreads();
    #pragma unroll
    for (int i = 0; i < 16; ++i) {
        int idx = tid + i*256;
        int cl = idx >> 6, r = idx & 63;
        const float* base = x + (size_t)(b*C_ + c0 + cl)*S_ + t*HW_;
        float v = base[indl[0][r]] + base[indl[1][r]] + base[indl[2][r]] + base[indl[3][r]];
        tile[cl][r] = 0.25f*v;
    }
    __syncthreads();
    #pragma unroll
    for (int i = 0; i < 16; ++i) {
        int idx = tid + i*256;
        int rl = idx >> 6, cl = idx & 63;
        ptsT[((size_t)b*P_ + t*64 + rl)*C_ + c0 + cl] = (f16)tile[cl][rl];
    }
}

// ============================================================
// K6: fuse_k via MFMA (gathered B rows via per-lane global addr)
// grid 256 = (bk<<3)|t; tile 128q x 64r; BK=32 dbuf + counted vmcnt + swizzle
// OUTPUT TRANSPOSED: fusekT[bk][p=t*64+r][q] f16 (q contiguous, f16x4 stores)
__global__ __launch_bounds__(256) void k_fuse(
    const f16* __restrict__ xT, const f16* __restrict__ wph,
    const float* __restrict__ wp,
    const float* __restrict__ g2, const float* __restrict__ b2,
    const float* __restrict__ m2, const float* __restrict__ v2,
    f16* __restrict__ fusekT, const int* __restrict__ inds)
{
    __shared__ __align__(16) f16 As[2][128*32];
    __shared__ __align__(16) f16 Bs[2][64*32];
    __shared__ float scq[128], shq[128], wrq[128], wcq[128];
    __shared__ float rowv[64], colv[64];
    int bid = blockIdx.x;
    int t = bid & 7, bk = bid >> 3;
    int b = bk >> 2;
    int tid = threadIdx.x;
    int lane = tid & 63, w = tid >> 6;
    // epilogue constants
    if (tid < 128) {
        float sc = g2[tid] * rsqrtf(v2[tid] + EPSB);
        scq[tid] = sc;
        shq[tid] = b2[tid] - m2[tid]*sc;
        wrq[tid] = wp[tid*514 + 512];
        wcq[tid] = wp[tid*514 + 513];
    } else if (tid < 192) {
        int r = tid - 128;
        int id = inds[bk*T_*R_ + t*R_ + r];
        rowv[r] = (float)(id / 28) * (1.0f/28.0f);
        colv[r] = (float)(id % 28) * (1.0f/28.0f);
    }
    // staging mapping: row = tid>>2 (0..63), slot = (tid&3) ^ (row&3)
    int strow = tid >> 2;
    int slot  = (tid & 3) ^ (strow & 3);
    int ind = inds[bk*T_*R_ + t*R_ + strow];
    const f16* ga = wph + (size_t)strow*C_ + slot*8;                   // q rows (0..63, +64)
    const f16* gb = xT + ((size_t)b*S_ + t*HW_ + ind)*C_ + slot*8;     // gathered r rows
    int mbase = (w & 1)*64, nbase = (w >> 1)*32;
    int fr = lane & 15, quad = lane >> 4;
    f32x4 acc[4][2] = {};
    __syncthreads();   // drain constant-setup loads before counted-vmcnt region
    // prologue stage step 0  (rows 64..127 live at f16 offset 64*32 = 2048)
    gload16(ga,         (f16*)As[0] + tid*8);
    gload16(ga + 64*C_, (f16*)As[0] + 2048 + tid*8);
    gload16(gb,         (f16*)Bs[0] + tid*8);
    ga += 32; gb += 32;
    int cur = 0;
    for (int i = 0; i < 16; ++i) {
        if (i < 15) {
            gload16(ga,         (f16*)As[cur^1] + tid*8);
            gload16(ga + 64*C_, (f16*)As[cur^1] + 2048 + tid*8);
            gload16(gb,         (f16*)Bs[cur^1] + tid*8);
            ga += 32; gb += 32;
            WAITV(3);
        } else {
            WAITV(0);
        }
        SCHB(); SBAR();
        f16x8 af[4], bf[2];
        #pragma unroll
        for (int mt = 0; mt < 4; ++mt) {
            int ar = mbase + mt*16 + fr;
            af[mt] = *(const f16x8*)&As[cur][ar*32 + ((quad ^ (ar & 3))*8)];
        }
        #pragma unroll
        for (int nt = 0; nt < 2; ++nt) {
            int br = nbase + nt*16 + fr;
            bf[nt] = *(const f16x8*)&Bs[cur][br*32 + ((quad ^ (br & 3))*8)];
        }
        #pragma unroll
        for (int mt = 0; mt < 4; ++mt)
            #pragma unroll
            for (int nt = 0; nt < 2; ++nt)
                acc[mt][nt] = __builtin_amdgcn_mfma_f32_16x16x32_f16(
                    af[mt], bf[nt], acc[mt][nt], 0, 0, 0);
        SBAR();
        cur ^= 1;
    }
    #pragma unroll
    for (int mt = 0; mt < 4; ++mt) {
        int qb = mbase + mt*16 + quad*4;
        #pragma unroll
        for (int nt = 0; nt < 2; ++nt) {
            int r = nbase + nt*16 + fr;
            f16x4 h;
            #pragma unroll
            for (int i = 0; i < 4; ++i) {
                int q = qb + i;
                float v = acc[mt][nt][i] + wrq[q]*rowv[r] + wcq[q]*colv[r];
                h[i] = (f16)(v*scq[q] + shq[q]);
            }
            *(f16x4*)&fusekT[((size_t)bk*P_ + t*R_ + r)*CQ_ + qb] = h;
        }
    }
}

// ============================================================
// K7: fuseT[b][p][q] f16 = max_k fusekT[b*4+k][p][q]
// grid 256: 65536 threads x f16x8
__global__ __launch_bounds__(256) void k_maxk(
    const f16* __restrict__ fusekT, f16* __restrict__ fuseT)
{
    int idx8 = (blockIdx.x*256 + threadIdx.x)*8;   // 524288 elems
    int b = idx8 >> 16;
    int pq = idx8 & 65535;
    const f16* base = fusekT + (size_t)(b*4)*65536 + pq;
    f16x8 v0 = *(const f16x8*)base;
    #pragma unroll
    for (int k = 1; k < K_; ++k) {
        f16x8 vk = *(const f16x8*)(base + (size_t)k*65536);
        #pragma unroll
        for (int j = 0; j < 8; ++j)
            v0[j] = (float)vk[j] > (float)v0[j] ? vk[j] : v0[j];
    }
    *(f16x8*)&fuseT[(size_t)b*65536 + pq] = v0;
}

// ============================================================
// K8: temporal conv via MFMA + bn3 + relu -> tc f16 [b][c][p]
// grid (4 p-tiles, 4 co-tiles, 8 b); tile 128co x 128p, K=384 over 6 steps
__global__ __launch_bounds__(256) void k_conv(
    const f16* __restrict__ wth,
    const float* __restrict__ g3, const float* __restrict__ b3,
    const float* __restrict__ m3, const float* __restrict__ v3,
    const f16* __restrict__ fuseT, f16* __restrict__ tc)
{
    __shared__ __align__(16) f16 As[128*64];   // p rows
    __shared__ __align__(16) f16 Bs[128*64];   // co rows
    int p0 = blockIdx.x*128, c0 = blockIdx.y*128, b = blockIdx.z;
    int tid = threadIdx.x;
    int lane = tid & 63, w = tid >> 6;
    int lrow = lane >> 3;
    int swzc = ((lane & 7) ^ lrow) * 8;
    int mrow = (w & 1)*64, nrow = (w >> 1)*64;
    int fr = lane & 15, quad = lane >> 4;
    int sw = fr & 7;
    f32x4 acc[4][4] = {};
    for (int step = 0; step < 6; ++step) {
        int dt = step >> 1, h = step & 1;
        int shift = (dt - 1)*64;
        #pragma unroll
        for (int j = 0; j < 4; ++j) {
            int rb = w*32 + j*8;
            int pg = p0 + rb + shift;          // 8-row group base in p'
            if (pg >= 0 && pg < P_)
                gload16(fuseT + ((size_t)b*P_ + pg + lrow)*CQ_ + h*64 + swzc,
                        &As[rb*64]);
            else
                *(f32x4*)((char*)&As[rb*64] + lane*16) = (f32x4){0.f,0.f,0.f,0.f};
        }
        #pragma unroll
        for (int j = 0; j < 4; ++j) {
            int rb = w*32 + j*8;
            gload16(wth + (size_t)(c0 + rb + lrow)*384 + dt*128 + h*64 + swzc,
                    &Bs[rb*64]);
        }
        __syncthreads();
        #pragma unroll
        for (int kk = 0; kk < 2; ++kk) {
            int ch = ((kk*4 + quad) ^ sw) * 8;
            f16x8 af[4], bf[4];
            #pragma unroll
            for (int mt = 0; mt < 4; ++mt)
                af[mt] = *(const f16x8*)&As[(mrow + mt*16 + fr)*64 + ch];
            #pragma unroll
            for (int nt = 0; nt < 4; ++nt)
                bf[nt] = *(const f16x8*)&Bs[(nrow + nt*16 + fr)*64 + ch];
            #pragma unroll
            for (int mt = 0; mt < 4; ++mt)
                #pragma unroll
                for (int nt = 0; nt < 4; ++nt)
                    acc[mt][nt] = __builtin_amdgcn_mfma_f32_16x16x32_f16(
                        af[mt], bf[nt], acc[mt][nt], 0, 0, 0);
        }
        __syncthreads();
    }
    #pragma unroll
    for (int nt = 0; nt < 4; ++nt) {
        int co = c0 + nrow + nt*16 + fr;
        float sc = g3[co] * rsqrtf(v3[co] + EPSB);
        float sh = b3[co] - m3[co]*sc;
        #pragma unroll
        for (int mt = 0; mt < 4; ++mt) {
            int p = p0 + mrow + mt*16 + quad*4;
            f16x4 hv;
            #pragma unroll
            for (int i = 0; i < 4; ++i)
                hv[i] = (f16)fmaxf(acc[mt][nt][i]*sc + sh, 0.f);
            *(f16x4*)&tc[((size_t)(b*C_ + co))*P_ + p] = hv;
        }
    }
}

// ============================================================
// K9: fused L-GEMM + row softmax (BK=32 dbuf + counted vmcnt):
//   L[s][p] = sum_c xT[s][c]*ptsT[p][c]  (full p=512 per block in registers)
//   W f16 = exp(L - rowmax), Dinv = 1/rowsum
// grid (cnt, 1, 8); 512 threads = 8 waves (2 s-halves x 4 p-quarters)
__global__ __launch_bounds__(512, 2) void k_attnW(
    const f16* __restrict__ xT, const f16* __restrict__ ptsT,
    f16* __restrict__ W, float* __restrict__ Dinv, int st, int NCHb)
{
    __shared__ __align__(16) f16 As[2][128*32];   // s rows (2 x 8 KB)
    __shared__ __align__(16) f16 Bs[2][512*32];   // p rows (2 x 32 KB)
    int lt = blockIdx.x; int b = blockIdx.z;
    int s0 = (st + lt)*128;
    int tid = threadIdx.x;
    int lane = tid & 63, w = tid >> 6;
    int wr = w & 1, wc = w >> 1;
    int strow = tid >> 2;                   // 0..127
    int slot  = (tid & 3) ^ (strow & 3);
    const f16* ga = xT   + ((size_t)b*S_ + s0 + strow)*C_ + slot*8;
    const f16* gb = ptsT + ((size_t)b*P_ + strow)*C_ + slot*8;     // +j*128 rows
    int fr = lane & 15, quad = lane >> 4;
    f32x4 acc[8][4] = {};                      // [nt over p][mt over s]
    // prologue stage step 0
    gload16(ga, (f16*)As[0] + tid*8);
    #pragma unroll
    for (int j = 0; j < 4; ++j)
        gload16(gb + (size_t)j*128*C_, (f16*)Bs[0] + j*4096 + tid*8);
    ga += 32; gb += 32;
    int cur = 0;
    for (int i = 0; i < 16; ++i) {
        if (i < 15) {
            gload16(ga, (f16*)As[cur^1] + tid*8);
            #pragma unroll
            for (int j = 0; j < 4; ++j)
                gload16(gb + (size_t)j*128*C_, (f16*)Bs[cur^1] + j*4096 + tid*8);
            ga += 32; gb += 32;
            WAITV(5);
        } else {
            WAITV(0);
        }
        SCHB(); SBAR();
        f16x8 af[4], bf[8];
        #pragma unroll
        for (int mt = 0; mt < 4; ++mt) {
            int ar = wr*64 + mt*16 + fr;
            af[mt] = *(const f16x8*)&As[cur][ar*32 + ((quad ^ (ar & 3))*8)];
        }
        #pragma unroll
        for (int nt = 0; nt < 8; ++nt) {
            int br = wc*128 + nt*16 + fr;
            bf[nt] = *(const f16x8*)&Bs[cur][br*32 + ((quad ^ (br & 3))*8)];
        }
        // swapped: C col = s (fr), C row = p (quad*4+i)
        #pragma unroll
        for (int nt = 0; nt < 8; ++nt)
            #pragma unroll
            for (int mt = 0; mt < 4; ++mt)
                acc[nt][mt] = __builtin_amdgcn_mfma_f32_16x16x32_f16(
                    bf[nt], af[mt], acc[nt][mt], 0, 0, 0);
        SBAR();
        cur ^= 1;
    }
    // ---- in-register softmax over p=512 per s-row (red aliased onto As) ----
    float (*red)[4] = (float (*)[4])As;
    float M[4];
    #pragma unroll
    for (int mt = 0; mt < 4; ++mt) {
        float m = -INFINITY;
        #pragma unroll
        for (int nt = 0; nt < 8; ++nt)
            #pragma unroll
            for (int i = 0; i < 4; ++i)
                m = fmaxf(m, acc[nt][mt][i]);
        m = fmaxf(m, __shfl_xor(m, 16));
        m = fmaxf(m, __shfl_xor(m, 32));
        if (quad == 0) red[wr*64 + mt*16 + fr][wc] = m;
    }
    __syncthreads();
    #pragma unroll
    for (int mt = 0; mt < 4; ++mt) {
        int srow = wr*64 + mt*16 + fr;
        M[mt] = fmaxf(fmaxf(red[srow][0], red[srow][1]),
                      fmaxf(red[srow][2], red[srow][3]));
    }
    __syncthreads();
    #pragma unroll
    for (int mt = 0; mt < 4; ++mt) {
        float s = 0.f;
        #pragma unroll
        for (int nt = 0; nt < 8; ++nt)
            #pragma unroll
            for (int i = 0; i < 4; ++i) {
                float e = __expf(acc[nt][mt][i] - M[mt]);
                acc[nt][mt][i] = e;
                s += e;
            }
        s += __shfl_xor(s, 16);
        s += __shfl_xor(s, 32);
        if (quad == 0) red[wr*64 + mt*16 + fr][wc] = s;
    }
    __syncthreads();
    size_t wbase = (size_t)(b*NCHb + lt)*128*(size_t)P_;
    #pragma unroll
    for (int mt = 0; mt < 4; ++mt) {
        int srow = wr*64 + mt*16 + fr;
        float tot = (red[srow][0] + red[srow][1]) + (red[srow][2] + red[srow][3]);
        if (wc == 0 && quad == 0)
            Dinv[(size_t)b*S_ + s0 + srow] = 1.0f/tot;
        #pragma unroll
        for (int nt = 0; nt < 8; ++nt) {
            f16x4 h;
            #pragma unroll
            for (int i = 0; i < 4; ++i) h[i] = (f16)acc[nt][mt][i];
            *(f16x4*)&W[wbase + (size_t)srow*P_ + wc*128 + nt*16 + quad*4] = h;
        }
    }
}

// ============================================================
// K11: out[b][c][s] = x + Dinv[s] * sum_p tc[b][c][p] * W[row(s)][p]
// grid (cnt, 4, 8); BK=64, swizzled LDS, dbuf + counted vmcnt
// NEW: x residual + Dinv preloaded into registers BEFORE the K-loop so
// their HBM latency hides under the GEMM (epilogue has no load tail).
__global__ __launch_bounds__(256) void k_gemmP(
    const f16* __restrict__ tc, const f16* __restrict__ W,
    const float* __restrict__ Dinv, const float* __restrict__ x,
    float* __restrict__ out, int st, int NCHb)
{
    __shared__ __align__(16) f16 As[2][128*64];
    __shared__ __align__(16) f16 Bs[2][128*64];
    int lt = blockIdx.x; int b = blockIdx.z;
    int s0 = (st + lt)*128, c0t = blockIdx.y*128;
    int tid = threadIdx.x;
    int lane = tid & 63, w = tid >> 6;
    int lrow = lane >> 3;
    int swzc = ((lane & 7) ^ lrow) * 8;
    const f16* ga = tc + ((size_t)(b*C_) + c0t + w*32 + lrow)*P_ + swzc;
    const f16* gb = W  + ((size_t)(b*NCHb + lt)*128 + w*32 + lrow)*P_ + swzc;
    int mrow = (w & 1)*64, nrow = (w >> 1)*64;
    int fr = lane & 15, quad = lane >> 4;
    int sw = fr & 7;
    f32x4 acc[4][4] = {};
    // ---- preload residual x and Dinv (latency hidden under K-loop) ----
    f32x4 xv[4][4], dv[4];
    #pragma unroll
    for (int nt = 0; nt < 4; ++nt) {
        int s = s0 + nrow + nt*16 + quad*4;
        dv[nt] = *(const f32x4*)&Dinv[(size_t)b*S_ + s];
        #pragma unroll
        for (int mt = 0; mt < 4; ++mt) {
            int c = c0t + mrow + mt*16 + fr;
            xv[nt][mt] = *(const f32x4*)&x[((size_t)(b*C_ + c))*S_ + s];
        }
    }
    #pragma unroll
    for (int j = 0; j < 4; ++j)
        gload16(ga + j*8*P_, &As[0][(w*32 + j*8)*64]);
    #pragma unroll
    for (int j = 0; j < 4; ++j)
        gload16(gb + j*8*P_, &Bs[0][(w*32 + j*8)*64]);
    ga += 64; gb += 64;
    int cur = 0;
    for (int i = 0; i < 8; ++i) {
        if (i < 7) {
            #pragma unroll
            for (int j = 0; j < 4; ++j)
                gload16(ga + j*8*P_, &As[cur^1][(w*32 + j*8)*64]);
            #pragma unroll
            for (int j = 0; j < 4; ++j)
                gload16(gb + j*8*P_, &Bs[cur^1][(w*32 + j*8)*64]);
            ga += 64; gb += 64;
            WAITV(8);
        } else {
            WAITV(0);
        }
        SCHB(); SBAR();
        #pragma unroll
        for (int kk = 0; kk < 2; ++kk) {
            int ch = ((kk*4 + quad) ^ sw) * 8;
            f16x8 af[4], bf[4];
            #pragma unroll
            for (int mt = 0; mt < 4; ++mt)
                af[mt] = *(const f16x8*)&As[cur][(mrow + mt*16 + fr)*64 + ch];
            #pragma unroll
            for (int nt = 0; nt < 4; ++nt)
                bf[nt] = *(const f16x8*)&Bs[cur][(nrow + nt*16 + fr)*64 + ch];
            // swapped: C row = s (from bf), C col = c (from af)
            #pragma unroll
            for (int nt = 0; nt < 4; ++nt)
                #pragma unroll
                for (int mt = 0; mt < 4; ++mt)
                    acc[nt][mt] = __builtin_amdgcn_mfma_f32_16x16x32_f16(
                        bf[nt], af[mt], acc[nt][mt], 0, 0, 0);
        }
        SBAR();
        cur ^= 1;
    }
    #pragma unroll
    for (int nt = 0; nt < 4; ++nt) {
        int s = s0 + nrow + nt*16 + quad*4;
        #pragma unroll
        for (int mt = 0; mt < 4; ++mt) {
            int c = c0t + mrow + mt*16 + fr;
            size_t o = ((size_t)(b*C_ + c))*S_ + s;
            f32x4 res = xv[nt][mt] + acc[nt][mt]*dv[nt];
            *(f32x4*)&out[o] = res;
        }
    }
}

// ============================================================
extern "C" void kernel_launch(void* const* d_in, const int* in_sizes, int n_in,
                              void* d_out, int out_size, void* d_ws, size_t ws_size,
                              hipStream_t stream) {
    const float* x   = (const float*)d_in[0];
    const float* wrd = (const float*)d_in[1];
    const float* g1  = (const float*)d_in[2];
    const float* v1  = (const float*)d_in[5];
    const float* wp  = (const float*)d_in[6];
    const float* g2  = (const float*)d_in[7];
    const float* b2  = (const float*)d_in[8];
    const float* m2  = (const float*)d_in[9];
    const float* v2  = (const float*)d_in[10];
    const float* wt  = (const float*)d_in[11];
    const float* g3  = (const float*)d_in[12];
    const float* b3  = (const float*)d_in[13];
    const float* m3  = (const float*)d_in[14];
    const float* v3  = (const float*)d_in[15];
    char*  wsb = (char*)d_ws;
    float* out = (float*)d_out;

    f16*   ptsT  = (f16*)  (wsb + OB_PTST);
    f16*   tc    = (f16*)  (wsb + OB_TC);
    float* Dinv  = (float*)(wsb + OB_D);
    f16*   trh   = (f16*)  (wsb + OB_TRH);
    float* trf   = (float*)(wsb + OB_TRF);
    int*   inds  = (int*)  (wsb + OB_INDS);
    f16*   wrh   = (f16*)  (wsb + OB_WRH);
    f16*   wph   = (f16*)  (wsb + OB_WPH);
    f16*   wth   = (f16*)  (wsb + OB_WTH);
    f16*   xT    = (f16*)  (wsb + OB_XT);
    float* tpa   = (float*)(wsb + T_TPA);
    float* aff   = (float*)(wsb + T_AFF);
    f16*   fusekT= (f16*)  (wsb + T_FUSEK);
    f16*   fuseT = (f16*)  (wsb + T_FUSE);

    // s-tile chunking (deterministic from ws_size -> graph-safe)
    const size_t PER_TILE = 1048576ull;   // W f16 per s-tile, all 8 batches
    size_t avail = ws_size > CHB ? ws_size - CHB : 0;
    int NCH = (int)(avail / PER_TILE);
    if (NCH < 1) NCH = 1;
    if (NCH > 49) NCH = 49;
    int nchunks = (49 + NCH - 1)/NCH;
    int NCHb = (49 + nchunks - 1)/nchunks;
    f16* W = (f16*)(wsb + CHB);

    k_prep<<<1152, 256, 0, stream>>>(wrd, wp, wt, wrh, wph, wth);
    k_xpose<<<dim3(98, 8, 8), 256, 0, stream>>>(x, xT);
    k_templ<<<dim3(7, 8), 256, 0, stream>>>(xT, wrh, tpa);
    k_targmax<<<512, 256, 0, stream>>>(x, wrd, g1, v1, tpa, trf, trh);
    k_affin<<<dim3(49, 8), 256, 0, stream>>>(xT, trh, aff);
    k_topk<<<dim3(R_, T_, B_), 256, 0, stream>>>(x, trf, aff, inds);
    k_pointsT<<<dim3(8, 8, 8), 256, 0, stream>>>(x, inds, ptsT);
    k_fuse<<<256, 256, 0, stream>>>(xT, wph, wp, g2, b2, m2, v2, fusekT, inds);
    k_maxk<<<256, 256, 0, stream>>>(fusekT, fuseT);
    k_conv<<<dim3(4, 4, 8), 256, 0, stream>>>(wth, g3, b3, m3, v3, fuseT, tc);

    for (int st = 0; st < 49; st += NCHb) {
        int cnt = (49 - st) < NCHb ? (49 - st) : NCHb;
        k_attnW<<<dim3(cnt, 1, 8), 512, 0, stream>>>(xT, ptsT, W, Dinv, st, NCHb);
        k_gemmP<<<dim3(cnt, 4, 8), 256, 0, stream>>>(tc, W, Dinv, x, out, st, NCHb);
    }
}

// Round 10
// 454.597 us; speedup vs baseline: 1.1102x; 1.0504x over previous
//
#include <hip/hip_runtime.h>

#define EPSB 1e-5f

// problem sizes
#define B_   8
#define C_   512
#define T_   8
#define HW_  784
#define S_   6272     // T*HW
#define R_   64
#define CQ_  128
#define K_   4
#define P_   512      // T*R

typedef _Float16 f16;
typedef __attribute__((ext_vector_type(8))) _Float16 f16x8;
typedef __attribute__((ext_vector_type(4))) _Float16 f16x4;
typedef __attribute__((ext_vector_type(4))) float    f32x4;

// ---- workspace byte offsets ----
#define OB_PTST  0ull                       // f16 [8][512][512]
#define OB_TC    4194304ull                 // f16 [8][512][512]
#define OB_D     8388608ull                 // (unused now)
#define OB_TRH   8589312ull                 // f16 [512][512]   (b*64+r rows)
#define OB_TRF   9113600ull                 // f32 [512][512]
#define OB_INDS  10162176ull                // int [8][4][8][64]
#define OB_WRH   10227712ull                // f16 [64][512]
#define OB_WPH   10293248ull                // f16 [128][512]  (w_proj cols 0..511)
#define OB_WTH   10424320ull                // f16 [512][3][128] (w_t repacked)
#define OB_XT    10817536ull                // f16 [8][6272][512]  51,380,224
// transients (region reused over time)
#define T_TPA    62197760ull                // f32 [512][784]
#define T_AFF    63803392ull                // f32 [512][6272]
#define T_FUSEK  62197760ull                // f16 [32][512][128]
#define T_FUSE   66392064ull                // f16 [8][512][128]  (fuseT, p-major)

#define SBAR()  __builtin_amdgcn_s_barrier()
#define SCHB()  __builtin_amdgcn_sched_barrier(0)
#define WAITV(N) asm volatile("s_waitcnt vmcnt(" #N ")" ::: "memory")

__device__ __forceinline__ void gload16(const void* g, void* l) {
    __builtin_amdgcn_global_load_lds(
        (const __attribute__((address_space(1))) unsigned int*)g,
        (__attribute__((address_space(3))) unsigned int*)l, 16, 0, 0);
}

// ============================================================
// P0: convert w_reduce -> f16 (32768), w_proj cols 0..511 -> f16 (65536),
//     w_t repack -> wth[co][dt][ci] f16 (196608)
__global__ __launch_bounds__(256) void k_prep(
    const float* __restrict__ wr, const float* __restrict__ wp,
    const float* __restrict__ wt,
    f16* __restrict__ wrh, f16* __restrict__ wph, f16* __restrict__ wth)
{
    int i = blockIdx.x*256 + threadIdx.x;   // 294912
    if (i < 32768) {
        wrh[i] = (f16)wr[i];
    } else if (i < 98304) {
        int j = i - 32768;
        int q = j >> 9, c = j & 511;
        wph[j] = (f16)wp[q*514 + c];
    } else {
        int j = i - 98304;                  // 196608 = 512*384
        int co = j / 384;
        int rem = j - co*384;
        int dt = rem >> 7, ci = rem & 127;
        wth[j] = (f16)wt[(size_t)(co*CQ_ + ci)*3 + dt];
    }
}

// ============================================================
// K0: transpose+convert x[b][c][s] f32 -> xT[b][s][c] f16
__global__ __launch_bounds__(256) void k_xpose(
    const float* __restrict__ x, f16* __restrict__ xT)
{
    __shared__ float tile[64][65];
    int s0 = blockIdx.x*64, c0 = blockIdx.y*64, b = blockIdx.z;
    int tid = threadIdx.x;
    #pragma unroll
    for (int i = 0; i < 4; ++i) {
        int idx = tid + i*256;
        int cl = idx >> 4, s4 = (idx & 15)*4;
        f32x4 v = *(const f32x4*)&x[((size_t)(b*C_ + c0+cl))*S_ + s0 + s4];
        tile[cl][s4] = v.x; tile[cl][s4+1] = v.y;
        tile[cl][s4+2] = v.z; tile[cl][s4+3] = v.w;
    }
    __syncthreads();
    #pragma unroll
    for (int i = 0; i < 4; ++i) {
        int idx = tid + i*256;
        int sl = idx >> 4, c4 = (idx & 15)*4;
        f16x4 h;
        h[0] = (f16)tile[c4+0][sl]; h[1] = (f16)tile[c4+1][sl];
        h[2] = (f16)tile[c4+2][sl]; h[3] = (f16)tile[c4+3][sl];
        *(f16x4*)&xT[((size_t)(b*S_ + s0+sl))*C_ + c0 + c4] = h;
    }
}

// ============================================================
// K1: template dots via MFMA: tpa[b*64+r][s] = sum_c wrh[r][c]*xT[b][s][c]
// grid (7, 8): tile 128s x 64r, BK=64, dbuf + counted vmcnt
__global__ __launch_bounds__(256) void k_templ(
    const f16* __restrict__ xT, const f16* __restrict__ wrh,
    float* __restrict__ tpa)
{
    __shared__ __align__(16) f16 As[2][128*64];
    __shared__ __align__(16) f16 Bs[2][64*64];
    int b = blockIdx.y; int s0 = blockIdx.x*128;
    int tid = threadIdx.x;
    int lane = tid & 63, w = tid >> 6;
    int lrow = lane >> 3;
    int swzc = ((lane & 7) ^ lrow) * 8;
    const f16* ga = xT  + ((size_t)b*S_ + s0 + w*32 + lrow)*C_ + swzc;
    const f16* gb = wrh + (size_t)(w*16 + lrow)*C_ + swzc;
    int mbase = (w & 1)*64, nbase = (w >> 1)*32;
    int fr = lane & 15, quad = lane >> 4;
    int sw = fr & 7;
    f32x4 acc[4][2] = {};
    #pragma unroll
    for (int j = 0; j < 4; ++j)
        gload16(ga + j*8*C_, &As[0][(w*32 + j*8)*64]);
    #pragma unroll
    for (int j = 0; j < 2; ++j)
        gload16(gb + j*8*C_, &Bs[0][(w*16 + j*8)*64]);
    ga += 64; gb += 64;
    int cur = 0;
    for (int i = 0; i < 8; ++i) {
        if (i < 7) {
            #pragma unroll
            for (int j = 0; j < 4; ++j)
                gload16(ga + j*8*C_, &As[cur^1][(w*32 + j*8)*64]);
            #pragma unroll
            for (int j = 0; j < 2; ++j)
                gload16(gb + j*8*C_, &Bs[cur^1][(w*16 + j*8)*64]);
            ga += 64; gb += 64;
            WAITV(6);
        } else {
            WAITV(0);
        }
        SCHB(); SBAR();
        #pragma unroll
        for (int kk = 0; kk < 2; ++kk) {
            int ch = ((kk*4 + quad) ^ sw) * 8;
            f16x8 af[4], bf[2];
            #pragma unroll
            for (int mt = 0; mt < 4; ++mt)
                af[mt] = *(const f16x8*)&As[cur][(mbase + mt*16 + fr)*64 + ch];
            #pragma unroll
            for (int nt = 0; nt < 2; ++nt)
                bf[nt] = *(const f16x8*)&Bs[cur][(nbase + nt*16 + fr)*64 + ch];
            #pragma unroll
            for (int mt = 0; mt < 4; ++mt)
                #pragma unroll
                for (int nt = 0; nt < 2; ++nt)
                    acc[mt][nt] = __builtin_amdgcn_mfma_f32_16x16x32_f16(
                        af[mt], bf[nt], acc[mt][nt], 0, 0, 0);
        }
        SBAR();
        cur ^= 1;
    }
    #pragma unroll
    for (int mt = 0; mt < 4; ++mt) {
        int sb = s0 + mbase + mt*16 + quad*4;
        if (sb < HW_) {
            #pragma unroll
            for (int nt = 0; nt < 2; ++nt) {
                int r = nbase + nt*16 + fr;
                *(f32x4*)&tpa[((size_t)(b*R_ + r))*HW_ + sb] = acc[mt][nt];
            }
        }
    }
}

// ============================================================
// K2: per (b,r): approx argmax of tpa*sc, gap-guarded exact fp32 fallback,
//     then gather tr row (f32 + f16)
// grid 512 = b*64+r
__global__ __launch_bounds__(256) void k_targmax(
    const float* __restrict__ x, const float* __restrict__ wr_g,
    const float* __restrict__ g1, const float* __restrict__ v1,
    const float* __restrict__ tpa,
    float* __restrict__ trf, f16* __restrict__ trh)
{
    __shared__ float row[HW_];
    __shared__ float sval[256];
    __shared__ int   sidx[256];
    __shared__ float cval[4];
    __shared__ int   cidx[4];
    __shared__ float eval_[4];
    __shared__ int   bestind;
    int bid = blockIdx.x;
    int b = bid >> 6, r = bid & 63;
    int tid = threadIdx.x;
    float sc = g1[r] * rsqrtf(v1[r] + EPSB);
    const float* tprow = tpa + (size_t)bid*HW_;
    for (int s = tid; s < HW_; s += 256) row[s] = tprow[s]*sc;
    __syncthreads();
    for (int pass = 0; pass < 4; ++pass) {
        float best = -INFINITY; int bi = 0;
        for (int s = tid; s < HW_; s += 256) {
            float v = row[s];
            if (v > best) { best = v; bi = s; }
        }
        sval[tid] = best; sidx[tid] = bi;
        __syncthreads();
        for (int off = 128; off > 0; off >>= 1) {
            if (tid < off) {
                float ov = sval[tid+off]; int oi = sidx[tid+off];
                if (ov > sval[tid] || (ov == sval[tid] && oi < sidx[tid])) {
                    sval[tid] = ov; sidx[tid] = oi;
                }
            }
            __syncthreads();
        }
        if (tid == 0) {
            cval[pass] = sval[0]; cidx[pass] = sidx[0];
            row[sidx[0]] = -INFINITY;
        }
        __syncthreads();
    }
    float thr = 0.05f * fabsf(sc);
    if (cval[0] - cval[1] >= thr) {
        if (tid == 0) bestind = cidx[0];
    } else {
        // exact fp32 recompute of the 4 candidates
        int w = tid >> 6, lane = tid & 63;
        int cand = cidx[w];
        float sum = 0.f;
        #pragma unroll
        for (int i = 0; i < 8; ++i) {
            int c = lane + i*64;
            sum += wr_g[r*C_ + c] * x[((size_t)(b*C_ + c))*S_ + cand];
        }
        #pragma unroll
        for (int off = 32; off > 0; off >>= 1) sum += __shfl_xor(sum, off);
        if (lane == 0) eval_[w] = sum*sc;
        __syncthreads();
        if (tid == 0) {
            float bv = eval_[0]; int bi2 = cidx[0];
            for (int j = 1; j < 4; ++j) {
                float v = eval_[j]; int ii = cidx[j];
                if (v > bv || (v == bv && ii < bi2)) { bv = v; bi2 = ii; }
            }
            bestind = bi2;
        }
    }
    __syncthreads();
    int ind = bestind;
    for (int c = tid; c < C_; c += 256) {
        float v = x[((size_t)(b*C_ + c))*S_ + ind];
        trf[(size_t)bid*C_ + c] = v;
        trh[(size_t)bid*C_ + c] = (f16)v;
    }
}

// ============================================================
// K3: affinity via MFMA: aff[b*64+r][s] = sum_c trh[b*64+r][c]*xT[b][s][c]
// grid (49, 8): tile 128s x 64r, BK=64, dbuf + counted vmcnt
__global__ __launch_bounds__(256) void k_affin(
    const f16* __restrict__ xT, const f16* __restrict__ trh,
    float* __restrict__ aff)
{
    __shared__ __align__(16) f16 As[2][128*64];
    __shared__ __align__(16) f16 Bs[2][64*64];
    int b = blockIdx.y; int s0 = blockIdx.x*128;
    int tid = threadIdx.x;
    int lane = tid & 63, w = tid >> 6;
    int lrow = lane >> 3;
    int swzc = ((lane & 7) ^ lrow) * 8;
    const f16* ga = xT  + ((size_t)b*S_ + s0 + w*32 + lrow)*C_ + swzc;
    const f16* gb = trh + ((size_t)(b*R_) + w*16 + lrow)*C_ + swzc;
    int mbase = (w & 1)*64, nbase = (w >> 1)*32;
    int fr = lane & 15, quad = lane >> 4;
    int sw = fr & 7;
    f32x4 acc[4][2] = {};
    #pragma unroll
    for (int j = 0; j < 4; ++j)
        gload16(ga + j*8*C_, &As[0][(w*32 + j*8)*64]);
    #pragma unroll
    for (int j = 0; j < 2; ++j)
        gload16(gb + j*8*C_, &Bs[0][(w*16 + j*8)*64]);
    ga += 64; gb += 64;
    int cur = 0;
    for (int i = 0; i < 8; ++i) {
        if (i < 7) {
            #pragma unroll
            for (int j = 0; j < 4; ++j)
                gload16(ga + j*8*C_, &As[cur^1][(w*32 + j*8)*64]);
            #pragma unroll
            for (int j = 0; j < 2; ++j)
                gload16(gb + j*8*C_, &Bs[cur^1][(w*16 + j*8)*64]);
            ga += 64; gb += 64;
            WAITV(6);
        } else {
            WAITV(0);
        }
        SCHB(); SBAR();
        #pragma unroll
        for (int kk = 0; kk < 2; ++kk) {
            int ch = ((kk*4 + quad) ^ sw) * 8;
            f16x8 af[4], bf[2];
            #pragma unroll
            for (int mt = 0; mt < 4; ++mt)
                af[mt] = *(const f16x8*)&As[cur][(mbase + mt*16 + fr)*64 + ch];
            #pragma unroll
            for (int nt = 0; nt < 2; ++nt)
                bf[nt] = *(const f16x8*)&Bs[cur][(nbase + nt*16 + fr)*64 + ch];
            #pragma unroll
            for (int mt = 0; mt < 4; ++mt)
                #pragma unroll
                for (int nt = 0; nt < 2; ++nt)
                    acc[mt][nt] = __builtin_amdgcn_mfma_f32_16x16x32_f16(
                        af[mt], bf[nt], acc[mt][nt], 0, 0, 0);
        }
        SBAR();
        cur ^= 1;
    }
    #pragma unroll
    for (int mt = 0; mt < 4; ++mt) {
        int sb = s0 + mbase + mt*16 + quad*4;
        #pragma unroll
        for (int nt = 0; nt < 2; ++nt) {
            int r = nbase + nt*16 + fr;
            *(f32x4*)&aff[((size_t)(b*R_ + r))*S_ + sb] = acc[mt][nt];
        }
    }
}

// ============================================================
// K4: per (b,t,r): approx top-8 of aff row, gap-guarded exact fp32 fallback,
//     write top-4 indices
// grid (64 r, 8 t, 8 b)
__global__ __launch_bounds__(256) void k_topk(
    const float* __restrict__ x, const float* __restrict__ trf,
    const float* __restrict__ aff, int* __restrict__ inds)
{
    __shared__ float row[HW_];
    __shared__ float sval[256];
    __shared__ int   sidx[256];
    __shared__ float cval[8];
    __shared__ int   cidx[8];
    __shared__ float eval_[8];
    int r = blockIdx.x, t = blockIdx.y, b = blockIdx.z;
    int tid = threadIdx.x;
    const float* arow = aff + ((size_t)(b*R_ + r))*S_ + t*HW_;
    for (int s = tid; s < HW_; s += 256) row[s] = arow[s];
    __syncthreads();
    for (int pass = 0; pass < 8; ++pass) {
        float best = -INFINITY; int bi = 0;
        for (int s = tid; s < HW_; s += 256) {
            float v = row[s];
            if (v > best) { best = v; bi = s; }
        }
        sval[tid] = best; sidx[tid] = bi;
        __syncthreads();
        for (int off = 128; off > 0; off >>= 1) {
            if (tid < off) {
                float ov = sval[tid+off]; int oi = sidx[tid+off];
                if (ov > sval[tid] || (ov == sval[tid] && oi < sidx[tid])) {
                    sval[tid] = ov; sidx[tid] = oi;
                }
            }
            __syncthreads();
        }
        if (tid == 0) {
            cval[pass] = sval[0]; cidx[pass] = sidx[0];
            row[sidx[0]] = -INFINITY;
        }
        __syncthreads();
    }
    if (cval[3] - cval[4] >= 0.35f) {
        if (tid < K_)
            inds[((b*K_ + tid)*T_ + t)*R_ + r] = cidx[tid];
    } else {
        // exact fp32 recompute of the 8 candidates
        int w = tid >> 6, lane = tid & 63;
        #pragma unroll
        for (int half = 0; half < 2; ++half) {
            int j = w + half*4;
            int cand = cidx[j];
            float sum = 0.f;
            #pragma unroll
            for (int i = 0; i < 8; ++i) {
                int c = lane + i*64;
                sum += trf[((size_t)(b*R_ + r))*C_ + c]
                     * x[((size_t)(b*C_ + c))*S_ + t*HW_ + cand];
            }
            #pragma unroll
            for (int off = 32; off > 0; off >>= 1) sum += __shfl_xor(sum, off);
            if (lane == 0) eval_[j] = sum;
        }
        __syncthreads();
        if (tid == 0) {
            unsigned used = 0;
            for (int k = 0; k < K_; ++k) {
                float bv = -INFINITY; int bj = -1;
                for (int j = 0; j < 8; ++j) {
                    if (used & (1u << j)) continue;
                    float v = eval_[j]; int ii = cidx[j];
                    if (bj < 0 || v > bv || (v == bv && ii < cidx[bj])) {
                        bv = v; bj = j;
                    }
                }
                used |= 1u << bj;
                inds[((b*K_ + k)*T_ + t)*R_ + r] = cidx[bj];
            }
        }
    }
}

// ============================================================
// K5: ptsT[b][p][c] f16 = mean_k x[b,c,t,ind],  p=t*64+r
__global__ __launch_bounds__(256) void k_pointsT(
    const float* __restrict__ x, const int* __restrict__ inds,
    f16* __restrict__ ptsT)
{
    __shared__ float tile[64][65];
    __shared__ int   indl[4][64];
    int c0 = blockIdx.x*64, t = blockIdx.y, b = blockIdx.z;
    int tid = threadIdx.x;
    {
        int k = tid >> 6, r = tid & 63;
        indl[k][r] = inds[((b*K_ + k)*T_ + t)*R_ + r];
    }
    __syncthreads();
    #pragma unroll
    for (int i = 0; i < 16; ++i) {
        int idx = tid + i*256;
        int cl = idx >> 6, r = idx & 63;
        const float* base = x + (size_t)(b*C_ + c0 + cl)*S_ + t*HW_;
        float v = base[indl[0][r]] + base[indl[1][r]] + base[indl[2][r]] + base[indl[3][r]];
        tile[cl][r] = 0.25f*v;
    }
    __syncthreads();
    #pragma unroll
    for (int i = 0; i < 16; ++i) {
        int idx = tid + i*256;
        int rl = idx >> 6, cl = idx & 63;
        ptsT[((size_t)b*P_ + t*64 + rl)*C_ + c0 + cl] = (f16)tile[cl][rl];
    }
}

// ============================================================
// K6: fuse_k via MFMA (gathered B rows via per-lane global addr)
// grid 256 = (bk<<3)|t; tile 128q x 64r; BK=32 dbuf + counted vmcnt + swizzle
// OUTPUT TRANSPOSED: fusekT[bk][p=t*64+r][q] f16 (q contiguous, f16x4 stores)
__global__ __launch_bounds__(256) void k_fuse(
    const f16* __restrict__ xT, const f16* __restrict__ wph,
    const float* __restrict__ wp,
    const float* __restrict__ g2, const float* __restrict__ b2,
    const float* __restrict__ m2, const float* __restrict__ v2,
    f16* __restrict__ fusekT, const int* __restrict__ inds)
{
    __shared__ __align__(16) f16 As[2][128*32];
    __shared__ __align__(16) f16 Bs[2][64*32];
    __shared__ float scq[128], shq[128], wrq[128], wcq[128];
    __shared__ float rowv[64], colv[64];
    int bid = blockIdx.x;
    int t = bid & 7, bk = bid >> 3;
    int b = bk >> 2;
    int tid = threadIdx.x;
    int lane = tid & 63, w = tid >> 6;
    // epilogue constants
    if (tid < 128) {
        float sc = g2[tid] * rsqrtf(v2[tid] + EPSB);
        scq[tid] = sc;
        shq[tid] = b2[tid] - m2[tid]*sc;
        wrq[tid] = wp[tid*514 + 512];
        wcq[tid] = wp[tid*514 + 513];
    } else if (tid < 192) {
        int r = tid - 128;
        int id = inds[bk*T_*R_ + t*R_ + r];
        rowv[r] = (float)(id / 28) * (1.0f/28.0f);
        colv[r] = (float)(id % 28) * (1.0f/28.0f);
    }
    // staging mapping: row = tid>>2 (0..63), slot = (tid&3) ^ (row&3)
    int strow = tid >> 2;
    int slot  = (tid & 3) ^ (strow & 3);
    int ind = inds[bk*T_*R_ + t*R_ + strow];
    const f16* ga = wph + (size_t)strow*C_ + slot*8;                   // q rows (0..63, +64)
    const f16* gb = xT + ((size_t)b*S_ + t*HW_ + ind)*C_ + slot*8;     // gathered r rows
    int mbase = (w & 1)*64, nbase = (w >> 1)*32;
    int fr = lane & 15, quad = lane >> 4;
    f32x4 acc[4][2] = {};
    __syncthreads();   // drain constant-setup loads before counted-vmcnt region
    // prologue stage step 0  (rows 64..127 live at f16 offset 64*32 = 2048)
    gload16(ga,         (f16*)As[0] + tid*8);
    gload16(ga + 64*C_, (f16*)As[0] + 2048 + tid*8);
    gload16(gb,         (f16*)Bs[0] + tid*8);
    ga += 32; gb += 32;
    int cur = 0;
    for (int i = 0; i < 16; ++i) {
        if (i < 15) {
            gload16(ga,         (f16*)As[cur^1] + tid*8);
            gload16(ga + 64*C_, (f16*)As[cur^1] + 2048 + tid*8);
            gload16(gb,         (f16*)Bs[cur^1] + tid*8);
            ga += 32; gb += 32;
            WAITV(3);
        } else {
            WAITV(0);
        }
        SCHB(); SBAR();
        f16x8 af[4], bf[2];
        #pragma unroll
        for (int mt = 0; mt < 4; ++mt) {
            int ar = mbase + mt*16 + fr;
            af[mt] = *(const f16x8*)&As[cur][ar*32 + ((quad ^ (ar & 3))*8)];
        }
        #pragma unroll
        for (int nt = 0; nt < 2; ++nt) {
            int br = nbase + nt*16 + fr;
            bf[nt] = *(const f16x8*)&Bs[cur][br*32 + ((quad ^ (br & 3))*8)];
        }
        #pragma unroll
        for (int mt = 0; mt < 4; ++mt)
            #pragma unroll
            for (int nt = 0; nt < 2; ++nt)
                acc[mt][nt] = __builtin_amdgcn_mfma_f32_16x16x32_f16(
                    af[mt], bf[nt], acc[mt][nt], 0, 0, 0);
        SBAR();
        cur ^= 1;
    }
    #pragma unroll
    for (int mt = 0; mt < 4; ++mt) {
        int qb = mbase + mt*16 + quad*4;
        #pragma unroll
        for (int nt = 0; nt < 2; ++nt) {
            int r = nbase + nt*16 + fr;
            f16x4 h;
            #pragma unroll
            for (int i = 0; i < 4; ++i) {
                int q = qb + i;
                float v = acc[mt][nt][i] + wrq[q]*rowv[r] + wcq[q]*colv[r];
                h[i] = (f16)(v*scq[q] + shq[q]);
            }
            *(f16x4*)&fusekT[((size_t)bk*P_ + t*R_ + r)*CQ_ + qb] = h;
        }
    }
}

// ============================================================
// K7: fuseT[b][p][q] f16 = max_k fusekT[b*4+k][p][q]
// grid 256: 65536 threads x f16x8
__global__ __launch_bounds__(256) void k_maxk(
    const f16* __restrict__ fusekT, f16* __restrict__ fuseT)
{
    int idx8 = (blockIdx.x*256 + threadIdx.x)*8;   // 524288 elems
    int b = idx8 >> 16;
    int pq = idx8 & 65535;
    const f16* base = fusekT + (size_t)(b*4)*65536 + pq;
    f16x8 v0 = *(const f16x8*)base;
    #pragma unroll
    for (int k = 1; k < K_; ++k) {
        f16x8 vk = *(const f16x8*)(base + (size_t)k*65536);
        #pragma unroll
        for (int j = 0; j < 8; ++j)
            v0[j] = (float)vk[j] > (float)v0[j] ? vk[j] : v0[j];
    }
    *(f16x8*)&fuseT[(size_t)b*65536 + pq] = v0;
}

// ============================================================
// K8: temporal conv via MFMA + bn3 + relu -> tc f16 [b][c][p]
// grid (4 p-tiles, 4 co-tiles, 8 b); tile 128co x 128p, K=384 over 6 steps
__global__ __launch_bounds__(256) void k_conv(
    const f16* __restrict__ wth,
    const float* __restrict__ g3, const float* __restrict__ b3,
    const float* __restrict__ m3, const float* __restrict__ v3,
    const f16* __restrict__ fuseT, f16* __restrict__ tc)
{
    __shared__ __align__(16) f16 As[128*64];   // p rows
    __shared__ __align__(16) f16 Bs[128*64];   // co rows
    int p0 = blockIdx.x*128, c0 = blockIdx.y*128, b = blockIdx.z;
    int tid = threadIdx.x;
    int lane = tid & 63, w = tid >> 6;
    int lrow = lane >> 3;
    int swzc = ((lane & 7) ^ lrow) * 8;
    int mrow = (w & 1)*64, nrow = (w >> 1)*64;
    int fr = lane & 15, quad = lane >> 4;
    int sw = fr & 7;
    f32x4 acc[4][4] = {};
    for (int step = 0; step < 6; ++step) {
        int dt = step >> 1, h = step & 1;
        int shift = (dt - 1)*64;
        #pragma unroll
        for (int j = 0; j < 4; ++j) {
            int rb = w*32 + j*8;
            int pg = p0 + rb + shift;          // 8-row group base in p'
            if (pg >= 0 && pg < P_)
                gload16(fuseT + ((size_t)b*P_ + pg + lrow)*CQ_ + h*64 + swzc,
                        &As[rb*64]);
            else
                *(f32x4*)((char*)&As[rb*64] + lane*16) = (f32x4){0.f,0.f,0.f,0.f};
        }
        #pragma unroll
        for (int j = 0; j < 4; ++j) {
            int rb = w*32 + j*8;
            gload16(wth + (size_t)(c0 + rb + lrow)*384 + dt*128 + h*64 + swzc,
                    &Bs[rb*64]);
        }
        __syncthreads();
        #pragma unroll
        for (int kk = 0; kk < 2; ++kk) {
            int ch = ((kk*4 + quad) ^ sw) * 8;
            f16x8 af[4], bf[4];
            #pragma unroll
            for (int mt = 0; mt < 4; ++mt)
                af[mt] = *(const f16x8*)&As[(mrow + mt*16 + fr)*64 + ch];
            #pragma unroll
            for (int nt = 0; nt < 4; ++nt)
                bf[nt] = *(const f16x8*)&Bs[(nrow + nt*16 + fr)*64 + ch];
            #pragma unroll
            for (int mt = 0; mt < 4; ++mt)
                #pragma unroll
                for (int nt = 0; nt < 4; ++nt)
                    acc[mt][nt] = __builtin_amdgcn_mfma_f32_16x16x32_f16(
                        af[mt], bf[nt], acc[mt][nt], 0, 0, 0);
        }
        __syncthreads();
    }
    #pragma unroll
    for (int nt = 0; nt < 4; ++nt) {
        int co = c0 + nrow + nt*16 + fr;
        float sc = g3[co] * rsqrtf(v3[co] + EPSB);
        float sh = b3[co] - m3[co]*sc;
        #pragma unroll
        for (int mt = 0; mt < 4; ++mt) {
            int p = p0 + mrow + mt*16 + quad*4;
            f16x4 hv;
            #pragma unroll
            for (int i = 0; i < 4; ++i)
                hv[i] = (f16)fmaxf(acc[mt][nt][i]*sc + sh, 0.f);
            *(f16x4*)&tc[((size_t)(b*C_ + co))*P_ + p] = hv;
        }
    }
}

// ============================================================
// K9: FUSED attention: L-GEMM + softmax (W kept in LDS) + PV-GEMM + residual
//   phase 1: L[s][p] = sum_c xT[s][c]*ptsT[p][c]; W = exp(L-max), dinv = 1/sum
//   phase 2: out[b][c][s0+s] = x + dinv[s] * sum_p tc[b][c][p] * W[s][p]
// grid (49, 8); 512 threads = 8 waves. LDS ~146.5 KB -> 1 block/CU.
__global__ __launch_bounds__(512, 2) void k_attnP(
    const f16* __restrict__ xT, const f16* __restrict__ ptsT,
    const f16* __restrict__ tc, const float* __restrict__ x,
    float* __restrict__ out)
{
    __shared__ __align__(16) char ldsb[150016];
    f16*  P1A  = (f16*)ldsb;                  // 2 bufs x 4096 f16 (xT rows)
    f16*  P1B  = (f16*)(ldsb + 16384);        // 2 bufs x 16384 f16 (ptsT rows)
    f16*  Wl   = (f16*)ldsb;                  // 128 x 512 f16 (reuses P1 region)
    f16*  TCs  = (f16*)(ldsb + 131072);       // 2 bufs x 4096 f16 (tc rows)
    float* dinv = (float*)(ldsb + 147456);    // 128 f32
    float (*red)[4] = (float (*)[4])(ldsb + 147968);  // [128][4]

    int lt = blockIdx.x, b = blockIdx.y;
    int s0 = lt*128;
    int tid = threadIdx.x;
    int lane = tid & 63, w = tid >> 6;
    int wr = w & 1, wc = w >> 1;
    int fr = lane & 15, quad = lane >> 4;

    // ---------------- phase 1 ----------------
    {
        int strow = tid >> 2;                   // 0..127
        int slot  = (tid & 3) ^ (strow & 3);
        const f16* ga = xT   + ((size_t)b*S_ + s0 + strow)*C_ + slot*8;
        const f16* gb = ptsT + ((size_t)b*P_ + strow)*C_ + slot*8;
        f32x4 acc[8][4] = {};                   // [nt over p][mt over s]
        gload16(ga, P1A + tid*8);
        #pragma unroll
        for (int j = 0; j < 4; ++j)
            gload16(gb + (size_t)j*128*C_, P1B + j*4096 + tid*8);
        ga += 32; gb += 32;
        int cur = 0;
        for (int i = 0; i < 16; ++i) {
            if (i < 15) {
                gload16(ga, P1A + (cur^1)*4096 + tid*8);
                #pragma unroll
                for (int j = 0; j < 4; ++j)
                    gload16(gb + (size_t)j*128*C_, P1B + (cur^1)*16384 + j*4096 + tid*8);
                ga += 32; gb += 32;
                WAITV(5);
            } else {
                WAITV(0);
            }
            SCHB(); SBAR();
            f16x8 af[4], bf[8];
            #pragma unroll
            for (int mt = 0; mt < 4; ++mt) {
                int ar = wr*64 + mt*16 + fr;
                af[mt] = *(const f16x8*)&P1A[cur*4096 + ar*32 + ((quad ^ (ar & 3))*8)];
            }
            #pragma unroll
            for (int nt = 0; nt < 8; ++nt) {
                int br = wc*128 + nt*16 + fr;
                bf[nt] = *(const f16x8*)&P1B[cur*16384 + br*32 + ((quad ^ (br & 3))*8)];
            }
            #pragma unroll
            for (int nt = 0; nt < 8; ++nt)
                #pragma unroll
                for (int mt = 0; mt < 4; ++mt)
                    acc[nt][mt] = __builtin_amdgcn_mfma_f32_16x16x32_f16(
                        bf[nt], af[mt], acc[nt][mt], 0, 0, 0);
            SBAR();
            cur ^= 1;
        }
        // in-register softmax over p=512 per s-row
        float M[4];
        #pragma unroll
        for (int mt = 0; mt < 4; ++mt) {
            float m = -INFINITY;
            #pragma unroll
            for (int nt = 0; nt < 8; ++nt)
                #pragma unroll
                for (int i = 0; i < 4; ++i)
                    m = fmaxf(m, acc[nt][mt][i]);
            m = fmaxf(m, __shfl_xor(m, 16));
            m = fmaxf(m, __shfl_xor(m, 32));
            if (quad == 0) red[wr*64 + mt*16 + fr][wc] = m;
        }
        __syncthreads();
        #pragma unroll
        for (int mt = 0; mt < 4; ++mt) {
            int srow = wr*64 + mt*16 + fr;
            M[mt] = fmaxf(fmaxf(red[srow][0], red[srow][1]),
                          fmaxf(red[srow][2], red[srow][3]));
        }
        __syncthreads();
        #pragma unroll
        for (int mt = 0; mt < 4; ++mt) {
            float s = 0.f;
            #pragma unroll
            for (int nt = 0; nt < 8; ++nt)
                #pragma unroll
                for (int i = 0; i < 4; ++i) {
                    float e = __expf(acc[nt][mt][i] - M[mt]);
                    acc[nt][mt][i] = e;
                    s += e;
                }
            s += __shfl_xor(s, 16);
            s += __shfl_xor(s, 32);
            if (quad == 0) red[wr*64 + mt*16 + fr][wc] = s;
        }
        __syncthreads();
        // write W (swizzled) + dinv into LDS (P1 staging dead by now)
        #pragma unroll
        for (int mt = 0; mt < 4; ++mt) {
            int srow = wr*64 + mt*16 + fr;
            float tot = (red[srow][0] + red[srow][1]) + (red[srow][2] + red[srow][3]);
            if (wc == 0 && quad == 0)
                dinv[srow] = 1.0f/tot;
            #pragma unroll
            for (int nt = 0; nt < 8; ++nt) {
                f16x4 h;
                #pragma unroll
                for (int i = 0; i < 4; ++i) h[i] = (f16)acc[nt][mt][i];
                int p0 = wc*128 + nt*16 + quad*4;
                int g  = p0 >> 3;
                int gp = (g & ~7) | ((g & 7) ^ (srow & 7));
                *(f16x4*)&Wl[srow*512 + gp*8 + (quad & 1)*4] = h;
            }
        }
    }
    __syncthreads();

    // ---------------- phase 2 ----------------
    int cgrp = w >> 2;          // 0..1
    int sgrp = w & 3;           // 0..3
    int tr = tid >> 3;          // 0..63 (tc chunk row)
    int tslot = (tid & 7) ^ (tr & 7);
    for (int c0 = 0; c0 < C_; c0 += 64) {
        const f16* gtc = tc + ((size_t)(b*C_) + c0 + tr)*P_ + tslot*8;
        f32x4 xv2[2][2], dv2[2], acc2[2][2];
        #pragma unroll
        for (int nt2 = 0; nt2 < 2; ++nt2) {
            int s = sgrp*32 + nt2*16 + quad*4;
            dv2[nt2] = *(const f32x4*)&dinv[s];
            #pragma unroll
            for (int mt2 = 0; mt2 < 2; ++mt2) {
                int c = c0 + cgrp*32 + mt2*16 + fr;
                xv2[nt2][mt2] = *(const f32x4*)&x[((size_t)(b*C_ + c))*S_ + s0 + s];
                acc2[nt2][mt2] = (f32x4){0.f,0.f,0.f,0.f};
            }
        }
        gload16(gtc, TCs + tid*8);
        gtc += 64;
        int cur2 = 0;
        for (int i2 = 0; i2 < 8; ++i2) {
            if (i2 < 7) {
                gload16(gtc, TCs + (cur2^1)*4096 + tid*8);
                gtc += 64;
                WAITV(1);
            } else {
                WAITV(0);
            }
            SCHB(); SBAR();
            #pragma unroll
            for (int kk = 0; kk < 2; ++kk) {
                f16x8 af2[2], bf2[2];
                #pragma unroll
                for (int mt2 = 0; mt2 < 2; ++mt2) {
                    int ar = cgrp*32 + mt2*16 + fr;
                    af2[mt2] = *(const f16x8*)&TCs[cur2*4096 + ar*64 + ((kk*4 + quad) ^ (ar & 7))*8];
                }
                #pragma unroll
                for (int nt2 = 0; nt2 < 2; ++nt2) {
                    int br = sgrp*32 + nt2*16 + fr;
                    int gp = i2*8 + ((kk*4 + quad) ^ (br & 7));
                    bf2[nt2] = *(const f16x8*)&Wl[br*512 + gp*8];
                }
                #pragma unroll
                for (int nt2 = 0; nt2 < 2; ++nt2)
                    #pragma unroll
                    for (int mt2 = 0; mt2 < 2; ++mt2)
                        acc2[nt2][mt2] = __builtin_amdgcn_mfma_f32_16x16x32_f16(
                            bf2[nt2], af2[mt2], acc2[nt2][mt2], 0, 0, 0);
            }
            SBAR();
            cur2 ^= 1;
        }
        #pragma unroll
        for (int nt2 = 0; nt2 < 2; ++nt2) {
            int s = sgrp*32 + nt2*16 + quad*4;
            #pragma unroll
            for (int mt2 = 0; mt2 < 2; ++mt2) {
                int c = c0 + cgrp*32 + mt2*16 + fr;
                size_t o = ((size_t)(b*C_ + c))*S_ + s0 + s;
                *(f32x4*)&out[o] = xv2[nt2][mt2] + acc2[nt2][mt2]*dv2[nt2];
            }
        }
    }
}

// ============================================================
extern "C" void kernel_launch(void* const* d_in, const int* in_sizes, int n_in,
                              void* d_out, int out_size, void* d_ws, size_t ws_size,
                              hipStream_t stream) {
    const float* x   = (const float*)d_in[0];
    const float* wrd = (const float*)d_in[1];
    const float* g1  = (const float*)d_in[2];
    const float* v1  = (const float*)d_in[5];
    const float* wp  = (const float*)d_in[6];
    const float* g2  = (const float*)d_in[7];
    const float* b2  = (const float*)d_in[8];
    const float* m2  = (const float*)d_in[9];
    const float* v2  = (const float*)d_in[10];
    const float* wt  = (const float*)d_in[11];
    const float* g3  = (const float*)d_in[12];
    const float* b3  = (const float*)d_in[13];
    const float* m3  = (const float*)d_in[14];
    const float* v3  = (const float*)d_in[15];
    char*  wsb = (char*)d_ws;
    float* out = (float*)d_out;

    f16*   ptsT  = (f16*)  (wsb + OB_PTST);
    f16*   tc    = (f16*)  (wsb + OB_TC);
    f16*   trh   = (f16*)  (wsb + OB_TRH);
    float* trf   = (float*)(wsb + OB_TRF);
    int*   inds  = (int*)  (wsb + OB_INDS);
    f16*   wrh   = (f16*)  (wsb + OB_WRH);
    f16*   wph   = (f16*)  (wsb + OB_WPH);
    f16*   wth   = (f16*)  (wsb + OB_WTH);
    f16*   xT    = (f16*)  (wsb + OB_XT);
    float* tpa   = (float*)(wsb + T_TPA);
    float* aff   = (float*)(wsb + T_AFF);
    f16*   fusekT= (f16*)  (wsb + T_FUSEK);
    f16*   fuseT = (f16*)  (wsb + T_FUSE);

    k_prep<<<1152, 256, 0, stream>>>(wrd, wp, wt, wrh, wph, wth);
    k_xpose<<<dim3(98, 8, 8), 256, 0, stream>>>(x, xT);
    k_templ<<<dim3(7, 8), 256, 0, stream>>>(xT, wrh, tpa);
    k_targmax<<<512, 256, 0, stream>>>(x, wrd, g1, v1, tpa, trf, trh);
    k_affin<<<dim3(49, 8), 256, 0, stream>>>(xT, trh, aff);
    k_topk<<<dim3(R_, T_, B_), 256, 0, stream>>>(x, trf, aff, inds);
    k_pointsT<<<dim3(8, 8, 8), 256, 0, stream>>>(x, inds, ptsT);
    k_fuse<<<256, 256, 0, stream>>>(xT, wph, wp, g2, b2, m2, v2, fusekT, inds);
    k_maxk<<<256, 256, 0, stream>>>(fusekT, fuseT);
    k_conv<<<dim3(4, 4, 8), 256, 0, stream>>>(wth, g3, b3, m3, v3, fuseT, tc);
    k_attnP<<<dim3(49, 8), 512, 0, stream>>>(xT, ptsT, tc, x, out);
}